// Round 1
// baseline (613.131 us; speedup 1.0000x reference)
//
#include <hip/hip_runtime.h>
#include <math.h>

// Problem constants (from setup_inputs): B=4, S=4096, H=1024, M=256, chunk=64
#define BB 4
#define SS 4096
#define HH 1024
#define MM 256
#define CHUNK 64
#define NCHUNK 64
#define ROWS (BB*SS)          // 16384
#define DECAY_F 0.99

// ---------------------------------------------------------------------------
// Generic C = A * B^T, row-major. C is (rows x ncols), A is (rows x K),
// Bm is (ncols x K). 64x64 block tile, BK=16, 256 threads, 4x4 per thread.
// ---------------------------------------------------------------------------
__global__ __launch_bounds__(256) void gemm_abt(const float* __restrict__ A,
                                                const float* __restrict__ Bm,
                                                float* __restrict__ C,
                                                int K, int ncols) {
  __shared__ float As[16][68];
  __shared__ float Bs[16][68];
  const int tid = threadIdx.x;
  const int ty = tid >> 4, tx = tid & 15;
  const int row0 = blockIdx.y * 64;
  const int col0 = blockIdx.x * 64;
  float acc[4][4] = {};
  for (int k0 = 0; k0 < K; k0 += 16) {
#pragma unroll
    for (int p = 0; p < 4; ++p) {
      int i = p * 256 + tid;
      int rr = i >> 4, kk = i & 15;
      As[kk][rr] = A[(size_t)(row0 + rr) * K + k0 + kk];
      Bs[kk][rr] = Bm[(size_t)(col0 + rr) * K + k0 + kk];
    }
    __syncthreads();
#pragma unroll
    for (int kk = 0; kk < 16; ++kk) {
      float a[4], b[4];
#pragma unroll
      for (int i = 0; i < 4; ++i) a[i] = As[kk][ty * 4 + i];
#pragma unroll
      for (int j = 0; j < 4; ++j) b[j] = Bs[kk][tx * 4 + j];
#pragma unroll
      for (int i = 0; i < 4; ++i)
#pragma unroll
        for (int j = 0; j < 4; ++j) acc[i][j] += a[i] * b[j];
    }
    __syncthreads();
  }
#pragma unroll
  for (int i = 0; i < 4; ++i)
#pragma unroll
    for (int j = 0; j < 4; ++j)
      C[(size_t)(row0 + ty * 4 + i) * ncols + col0 + tx * 4 + j] = acc[i][j];
}

// ---------------------------------------------------------------------------
// L2-normalize rows of length 256 (fp32). One wave per row, float4 per lane.
// ---------------------------------------------------------------------------
__global__ __launch_bounds__(256) void l2norm_rows(float* __restrict__ data,
                                                   int nrows) {
  int wave = blockIdx.x * 4 + (threadIdx.x >> 6);
  int lane = threadIdx.x & 63;
  if (wave >= nrows) return;
  float4* p = reinterpret_cast<float4*>(data + (size_t)wave * MM);
  float4 v = p[lane];
  float ss = v.x * v.x + v.y * v.y + v.z * v.z + v.w * v.w;
#pragma unroll
  for (int off = 32; off; off >>= 1) ss += __shfl_xor(ss, off);
  float inv = 1.0f / fmaxf(sqrtf(ss), 1e-12f);
  v.x *= inv; v.y *= inv; v.z *= inv; v.w *= inv;
  p[lane] = v;
}

// ---------------------------------------------------------------------------
// outer[t][i][j] = scale * sum_{b,c} v[b, t*64+c, i] * k[b, t*64+c, j]
// grid: (jtile=4, itile=4, t=64)
// ---------------------------------------------------------------------------
__global__ __launch_bounds__(256) void outer_kernel(const float* __restrict__ v,
                                                    const float* __restrict__ kmat,
                                                    float* __restrict__ outer,
                                                    float scale) {
  __shared__ float Vs[16][68];
  __shared__ float Ks[16][68];
  const int t = blockIdx.z;
  const int i0 = blockIdx.y * 64, j0 = blockIdx.x * 64;
  const int tid = threadIdx.x, ty = tid >> 4, tx = tid & 15;
  float acc[4][4] = {};
  for (int r0 = 0; r0 < BB * CHUNK; r0 += 16) {
#pragma unroll
    for (int p = 0; p < 4; ++p) {
      int i = p * 256 + tid;        // 1024 elems: rr(16) x ii(64)
      int rr = i >> 6, ii = i & 63;
      int r = r0 + rr;
      size_t grow = ((size_t)(r >> 6) * SS + (size_t)t * CHUNK + (r & 63)) * MM;
      Vs[rr][ii] = v[grow + i0 + ii];
      Ks[rr][ii] = kmat[grow + j0 + ii];
    }
    __syncthreads();
#pragma unroll
    for (int rr = 0; rr < 16; ++rr) {
      float a[4], b[4];
#pragma unroll
      for (int i = 0; i < 4; ++i) a[i] = Vs[rr][ty * 4 + i];
#pragma unroll
      for (int j = 0; j < 4; ++j) b[j] = Ks[rr][tx * 4 + j];
#pragma unroll
      for (int i = 0; i < 4; ++i)
#pragma unroll
        for (int j = 0; j < 4; ++j) acc[i][j] += a[i] * b[j];
    }
    __syncthreads();
  }
  size_t base = (size_t)t * MM * MM;
#pragma unroll
  for (int i = 0; i < 4; ++i)
#pragma unroll
    for (int j = 0; j < 4; ++j)
      outer[base + (size_t)(i0 + ty * 4 + i) * MM + j0 + tx * 4 + j] =
          scale * acc[i][j];
}

// ---------------------------------------------------------------------------
// In-place decay prefix over t (elementwise in (i,j)):
//   Mprev[0] = M0;  Mprev[t] = decay*Mprev[t-1] + outer[t-1]
// outer[t] is overwritten with Mprev[t].
// ---------------------------------------------------------------------------
__global__ __launch_bounds__(256) void prefix_kernel(float* __restrict__ outer,
                                                     const float* __restrict__ M0,
                                                     float decay_c) {
  int ij = blockIdx.x * 256 + threadIdx.x;   // 65536 entries
  float running = M0[ij];
#pragma unroll 1
  for (int t = 0; t < NCHUNK; ++t) {
    float* p = outer + (size_t)t * MM * MM + ij;
    float o = *p;
    *p = running;
    running = decay_c * running + o;
  }
}

// ---------------------------------------------------------------------------
// r[b, t*64+c, n] = sum_m q[b, t*64+c, m] * Mprev[t][n][m]
// grid: (ntile=4, t=64, b=4)
// ---------------------------------------------------------------------------
__global__ __launch_bounds__(256) void retrieve_kernel(const float* __restrict__ q,
                                                       const float* __restrict__ Mprev,
                                                       float* __restrict__ r) {
  __shared__ float Qs[16][68];
  __shared__ float Ms[16][68];
  const int nt = blockIdx.x, t = blockIdx.y, b = blockIdx.z;
  const int tid = threadIdx.x, ty = tid >> 4, tx = tid & 15;
  const size_t rowbase = (size_t)b * SS + (size_t)t * CHUNK;
  const float* Mt = Mprev + (size_t)t * MM * MM + (size_t)nt * 64 * MM;
  float acc[4][4] = {};
  for (int m0 = 0; m0 < MM; m0 += 16) {
#pragma unroll
    for (int p = 0; p < 4; ++p) {
      int i = p * 256 + tid;
      int rr = i >> 4, kk = i & 15;
      Qs[kk][rr] = q[(rowbase + rr) * MM + m0 + kk];
      Ms[kk][rr] = Mt[(size_t)rr * MM + m0 + kk];
    }
    __syncthreads();
#pragma unroll
    for (int kk = 0; kk < 16; ++kk) {
      float a[4], bb[4];
#pragma unroll
      for (int i = 0; i < 4; ++i) a[i] = Qs[kk][ty * 4 + i];
#pragma unroll
      for (int j = 0; j < 4; ++j) bb[j] = Ms[kk][tx * 4 + j];
#pragma unroll
      for (int i = 0; i < 4; ++i)
#pragma unroll
        for (int j = 0; j < 4; ++j) acc[i][j] += a[i] * bb[j];
    }
    __syncthreads();
  }
  const int n0 = nt * 64;
#pragma unroll
  for (int i = 0; i < 4; ++i)
#pragma unroll
    for (int j = 0; j < 4; ++j)
      r[(rowbase + ty * 4 + i) * MM + n0 + tx * 4 + j] = acc[i][j];
}

// ---------------------------------------------------------------------------
extern "C" void kernel_launch(void* const* d_in, const int* in_sizes, int n_in,
                              void* d_out, int out_size, void* d_ws, size_t ws_size,
                              hipStream_t stream) {
  const float* x  = (const float*)d_in[0];   // (4,4096,1024)
  const float* Wq = (const float*)d_in[1];   // (256,1024)
  const float* Wk = (const float*)d_in[2];
  const float* Wv = (const float*)d_in[3];
  const float* Wo = (const float*)d_in[4];   // (1024,256)
  const float* M0 = (const float*)d_in[5];   // (256,256)
  float* out = (float*)d_out;                // (4,4096,1024) fp32

  const size_t QKV = (size_t)ROWS * MM;      // 4,194,304 elems = 16 MB
  float* q     = (float*)d_ws;
  float* kmat  = q + QKV;
  float* vmat  = kmat + QKV;
  float* outer = vmat + QKV;                 // 64 x 256 x 256
  float* r     = kmat;                       // k is dead after outer_kernel

  const float scale   = 1.0f / (BB * CHUNK);
  const float decay_c = (float)pow(DECAY_F, (double)CHUNK);

  dim3 blk(256);
  // 1) projections
  gemm_abt<<<dim3(MM / 64, ROWS / 64), blk, 0, stream>>>(x, Wq, q,    HH, MM);
  gemm_abt<<<dim3(MM / 64, ROWS / 64), blk, 0, stream>>>(x, Wk, kmat, HH, MM);
  gemm_abt<<<dim3(MM / 64, ROWS / 64), blk, 0, stream>>>(x, Wv, vmat, HH, MM);
  // 2) normalize k and v (contiguous in ws -> one launch over 2*ROWS rows)
  l2norm_rows<<<(2 * ROWS) / 4, blk, 0, stream>>>(kmat, 2 * ROWS);
  // 3) per-chunk outer products
  outer_kernel<<<dim3(4, 4, NCHUNK), blk, 0, stream>>>(vmat, kmat, outer, scale);
  // 4) decay prefix scan (in place: outer[t] -> Mprev[t])
  prefix_kernel<<<(MM * MM) / 256, blk, 0, stream>>>(outer, M0, decay_c);
  // 5) retrieval r = q @ Mprev^T (writes into k's old buffer)
  retrieve_kernel<<<dim3(4, NCHUNK, BB), blk, 0, stream>>>(q, outer, r);
  // 6) output projection
  gemm_abt<<<dim3(HH / 64, ROWS / 64), blk, 0, stream>>>(r, Wo, out, MM, HH);
}

// Round 2
// 195.062 us; speedup vs baseline: 3.1433x; 3.1433x over previous
//
#include <hip/hip_runtime.h>
#include <math.h>

// Problem constants: B=4, S=4096, H=1024, M=256, chunk=64
#define BB 4
#define SS 4096
#define HH 1024
#define MM 256
#define CHUNK 64
#define NCHUNK 64
#define ROWS (BB*SS)          // 16384
#define QKV_LD 768
#define DECAY_F 0.99

typedef unsigned short u16;
typedef __attribute__((ext_vector_type(8))) short bf16x8;
typedef __attribute__((ext_vector_type(4))) float f32x4;

__device__ inline u16 f2b(float f) {
  union { float f; unsigned u; } v; v.f = f;
  unsigned r = v.u + 0x7FFF + ((v.u >> 16) & 1);   // RNE
  return (u16)(r >> 16);
}
__device__ inline float b2f(u16 h) {
  union { unsigned u; float f; } v; v.u = ((unsigned)h) << 16; return v.f;
}

// ---------------------------------------------------------------------------
// fp32 -> bf16 cast, 4 elems/thread
// ---------------------------------------------------------------------------
__global__ __launch_bounds__(256) void cast_f2b_kernel(const float* __restrict__ src,
                                                       u16* __restrict__ dst, int n4) {
  int i = blockIdx.x * 256 + threadIdx.x;
  if (i >= n4) return;
  float4 v = reinterpret_cast<const float4*>(src)[i];
  ushort4 o;
  o.x = f2b(v.x); o.y = f2b(v.y); o.z = f2b(v.z); o.w = f2b(v.w);
  reinterpret_cast<ushort4*>(dst)[i] = o;
}

// ---------------------------------------------------------------------------
// C = A * B^T with bf16 A (rows x K), bf16 B (ncols x K), both row-major,
// K-contiguous. 128x128 tile, BK=32, 256 thr = 4 waves, each wave 64x64 via
// 4x4 frags of mfma_f32_16x16x32_bf16. Fragment-major LDS (conflict-free).
// ---------------------------------------------------------------------------
template<int OUT_BF16>
__global__ __launch_bounds__(256) void gemm_bt_mfma(const u16* __restrict__ A,
                                                    const u16* __restrict__ B,
                                                    void* __restrict__ Cv,
                                                    int K, int ldc) {
  __shared__ bf16x8 As[512];   // 8 KB: slot = mtile*64 + lane
  __shared__ bf16x8 Bs[512];
  const int tid  = threadIdx.x;
  const int lane = tid & 63;
  const int wv   = tid >> 6;
  const int wr   = wv >> 1, wc = wv & 1;       // wave -> 64x64 sub-tile
  const size_t row0 = (size_t)blockIdx.y * 128;
  const size_t col0 = (size_t)blockIdx.x * 128;

  // staging slots: s0 = tid (mtiles 0..3), s1 = tid+256 (mtiles 4..7)
  const int s0 = tid, s1 = tid + 256;
  const int l0 = s0 & 63, l1 = s1 & 63;
  const int rA0 = ((s0 >> 6) << 4) | (l0 & 15), kA0 = l0 >> 4;
  const int rA1 = ((s1 >> 6) << 4) | (l1 & 15), kA1 = l1 >> 4;
  const u16* pA0 = A + (row0 + rA0) * (size_t)K + kA0 * 8;
  const u16* pA1 = A + (row0 + rA1) * (size_t)K + kA1 * 8;
  const u16* pB0 = B + (col0 + rA0) * (size_t)K + kA0 * 8;
  const u16* pB1 = B + (col0 + rA1) * (size_t)K + kA1 * 8;

  f32x4 acc[4][4] = {};

  for (int k0 = 0; k0 < K; k0 += 32) {
    bf16x8 a0 = *reinterpret_cast<const bf16x8*>(pA0 + k0);
    bf16x8 a1 = *reinterpret_cast<const bf16x8*>(pA1 + k0);
    bf16x8 b0 = *reinterpret_cast<const bf16x8*>(pB0 + k0);
    bf16x8 b1 = *reinterpret_cast<const bf16x8*>(pB1 + k0);
    __syncthreads();                 // previous iter's frag reads done
    As[s0] = a0; As[s1] = a1;
    Bs[s0] = b0; Bs[s1] = b1;
    __syncthreads();
    bf16x8 af[4], bf[4];
#pragma unroll
    for (int m = 0; m < 4; ++m) af[m] = As[(wr * 4 + m) * 64 + lane];
#pragma unroll
    for (int n = 0; n < 4; ++n) bf[n] = Bs[(wc * 4 + n) * 64 + lane];
#pragma unroll
    for (int m = 0; m < 4; ++m)
#pragma unroll
      for (int n = 0; n < 4; ++n)
        acc[m][n] = __builtin_amdgcn_mfma_f32_16x16x32_bf16(af[m], bf[n], acc[m][n], 0, 0, 0);
  }

  // C/D layout: col = lane&15, row = (lane>>4)*4 + reg  [guide m89]
  const int r4 = (lane >> 4) * 2 * 2;   // (lane>>4)*4
  const int cc = lane & 15;
#pragma unroll
  for (int m = 0; m < 4; ++m)
#pragma unroll
    for (int n = 0; n < 4; ++n) {
      size_t rbase = row0 + wr * 64 + m * 16 + r4;
      size_t cbase = col0 + wc * 64 + n * 16 + cc;
      if (OUT_BF16) {
        u16* C = (u16*)Cv;
#pragma unroll
        for (int r = 0; r < 4; ++r) C[(rbase + r) * ldc + cbase] = f2b(acc[m][n][r]);
      } else {
        float* C = (float*)Cv;
#pragma unroll
        for (int r = 0; r < 4; ++r) C[(rbase + r) * ldc + cbase] = acc[m][n][r];
      }
    }
}

// ---------------------------------------------------------------------------
// L2-normalize the k and v segments (cols [256,512) and [512,768)) of each
// qkv row, in place, bf16. One wave per (row, which).
// ---------------------------------------------------------------------------
__global__ __launch_bounds__(256) void l2norm_bf16(u16* __restrict__ qkv) {
  int wave = blockIdx.x * 4 + (threadIdx.x >> 6);
  int lane = threadIdx.x & 63;
  int row = wave >> 1, which = wave & 1;
  u16* p = qkv + (size_t)row * QKV_LD + 256 + which * 256 + lane * 4;
  ushort4 h = *reinterpret_cast<ushort4*>(p);
  float f0 = b2f(h.x), f1 = b2f(h.y), f2 = b2f(h.z), f3 = b2f(h.w);
  float ss = f0 * f0 + f1 * f1 + f2 * f2 + f3 * f3;
#pragma unroll
  for (int off = 32; off; off >>= 1) ss += __shfl_xor(ss, off);
  float inv = 1.0f / fmaxf(sqrtf(ss), 1e-12f);
  h.x = f2b(f0 * inv); h.y = f2b(f1 * inv); h.z = f2b(f2 * inv); h.w = f2b(f3 * inv);
  *reinterpret_cast<ushort4*>(p) = h;
}

// ---------------------------------------------------------------------------
// outer[t][i][j] = scale * sum_{b,c} v[b,t*64+c,i] * k[b,t*64+c,j]
// v = qkv col 512, k = qkv col 256 (bf16, ld 768). fp32 accumulate.
// ---------------------------------------------------------------------------
__global__ __launch_bounds__(256) void outer_kernel(const u16* __restrict__ qkv,
                                                    float* __restrict__ outer,
                                                    float scale) {
  __shared__ float Vs[16][68];
  __shared__ float Ks[16][68];
  const int t = blockIdx.z;
  const int i0 = blockIdx.y * 64, j0 = blockIdx.x * 64;
  const int tid = threadIdx.x, ty = tid >> 4, tx = tid & 15;
  float acc[4][4] = {};
  for (int r0 = 0; r0 < BB * CHUNK; r0 += 16) {
#pragma unroll
    for (int p = 0; p < 4; ++p) {
      int i = p * 256 + tid;
      int rr = i >> 6, ii = i & 63;
      int r = r0 + rr;
      size_t grow = ((size_t)(r >> 6) * SS + (size_t)t * CHUNK + (r & 63)) * QKV_LD;
      Vs[rr][ii] = b2f(qkv[grow + 512 + i0 + ii]);
      Ks[rr][ii] = b2f(qkv[grow + 256 + j0 + ii]);
    }
    __syncthreads();
#pragma unroll
    for (int rr = 0; rr < 16; ++rr) {
      float a[4], b[4];
#pragma unroll
      for (int i = 0; i < 4; ++i) a[i] = Vs[rr][ty * 4 + i];
#pragma unroll
      for (int j = 0; j < 4; ++j) b[j] = Ks[rr][tx * 4 + j];
#pragma unroll
      for (int i = 0; i < 4; ++i)
#pragma unroll
        for (int j = 0; j < 4; ++j) acc[i][j] += a[i] * b[j];
    }
    __syncthreads();
  }
  size_t base = (size_t)t * MM * MM;
#pragma unroll
  for (int i = 0; i < 4; ++i)
#pragma unroll
    for (int j = 0; j < 4; ++j)
      outer[base + (size_t)(i0 + ty * 4 + i) * MM + j0 + tx * 4 + j] = scale * acc[i][j];
}

// ---------------------------------------------------------------------------
// Decay prefix over t (elementwise): outer[t] -> Mprev[t], in place. fp32.
// ---------------------------------------------------------------------------
__global__ __launch_bounds__(256) void prefix_kernel(float* __restrict__ outer,
                                                     const float* __restrict__ M0,
                                                     float decay_c) {
  int ij = blockIdx.x * 256 + threadIdx.x;
  float running = M0[ij];
#pragma unroll 1
  for (int t = 0; t < NCHUNK; ++t) {
    float* p = outer + (size_t)t * MM * MM + ij;
    float o = *p;
    *p = running;
    running = decay_c * running + o;
  }
}

// ---------------------------------------------------------------------------
// r[b,t*64+c,n] = sum_m q[b,t*64+c,m] * Mprev[t][n][m]; q bf16 (ld 768),
// Mprev fp32, r written as bf16 (ld 256).
// ---------------------------------------------------------------------------
__global__ __launch_bounds__(256) void retrieve_kernel(const u16* __restrict__ qkv,
                                                       const float* __restrict__ Mprev,
                                                       u16* __restrict__ r) {
  __shared__ float Qs[16][68];
  __shared__ float Ms[16][68];
  const int nt = blockIdx.x, t = blockIdx.y, b = blockIdx.z;
  const int tid = threadIdx.x, ty = tid >> 4, tx = tid & 15;
  const size_t rowbase = (size_t)b * SS + (size_t)t * CHUNK;
  const float* Mt = Mprev + (size_t)t * MM * MM + (size_t)nt * 64 * MM;
  float acc[4][4] = {};
  for (int m0 = 0; m0 < MM; m0 += 16) {
#pragma unroll
    for (int p = 0; p < 4; ++p) {
      int i = p * 256 + tid;
      int rr = i >> 4, kk = i & 15;
      Qs[kk][rr] = b2f(qkv[(rowbase + rr) * QKV_LD + m0 + kk]);
      Ms[kk][rr] = Mt[(size_t)rr * MM + m0 + kk];
    }
    __syncthreads();
#pragma unroll
    for (int kk = 0; kk < 16; ++kk) {
      float a[4], bb[4];
#pragma unroll
      for (int i = 0; i < 4; ++i) a[i] = Qs[kk][ty * 4 + i];
#pragma unroll
      for (int j = 0; j < 4; ++j) bb[j] = Ms[kk][tx * 4 + j];
#pragma unroll
      for (int i = 0; i < 4; ++i)
#pragma unroll
        for (int j = 0; j < 4; ++j) acc[i][j] += a[i] * bb[j];
    }
    __syncthreads();
  }
  const int n0 = nt * 64;
#pragma unroll
  for (int i = 0; i < 4; ++i)
#pragma unroll
    for (int j = 0; j < 4; ++j)
      r[(rowbase + ty * 4 + i) * MM + n0 + tx * 4 + j] = f2b(acc[i][j]);
}

// ---------------------------------------------------------------------------
extern "C" void kernel_launch(void* const* d_in, const int* in_sizes, int n_in,
                              void* d_out, int out_size, void* d_ws, size_t ws_size,
                              hipStream_t stream) {
  const float* x  = (const float*)d_in[0];
  const float* Wq = (const float*)d_in[1];
  const float* Wk = (const float*)d_in[2];
  const float* Wv = (const float*)d_in[3];
  const float* Wo = (const float*)d_in[4];
  const float* M0 = (const float*)d_in[5];
  float* out = (float*)d_out;

  char* ws = (char*)d_ws;
  // layout (bytes): [0,32M) xb  -> later reused: [0,16M) outer, [16M,24M) r_b
  u16*   xb      = (u16*)(ws);                              // 16384x1024 bf16
  u16*   qkv_b   = (u16*)(ws + 33554432);                   // 16384x768 bf16
  u16*   Wqkv_b  = (u16*)(ws + 58720256);                   // 768x1024 bf16
  u16*   Wo_b    = (u16*)(ws + 60293120);                   // 1024x256 bf16
  float* outer   = (float*)(ws);                            // 64x256x256 f32
  u16*   r_b     = (u16*)(ws + 16777216);                   // 16384x256 bf16

  const float scale   = 1.0f / (BB * CHUNK);
  const float decay_c = (float)pow(DECAY_F, (double)CHUNK);
  dim3 blk(256);

  // 1) casts
  cast_f2b_kernel<<<(ROWS * HH / 4) / 256, blk, 0, stream>>>(x, xb, ROWS * HH / 4);
  cast_f2b_kernel<<<(MM * HH / 4) / 256, blk, 0, stream>>>(Wq, Wqkv_b, MM * HH / 4);
  cast_f2b_kernel<<<(MM * HH / 4) / 256, blk, 0, stream>>>(Wk, Wqkv_b + MM * HH, MM * HH / 4);
  cast_f2b_kernel<<<(MM * HH / 4) / 256, blk, 0, stream>>>(Wv, Wqkv_b + 2 * MM * HH, MM * HH / 4);
  cast_f2b_kernel<<<(HH * MM / 4) / 256, blk, 0, stream>>>(Wo, Wo_b, HH * MM / 4);
  // 2) fused QKV projection (bf16 MFMA): (16384x1024)x(768x1024)^T
  gemm_bt_mfma<1><<<dim3(QKV_LD / 128, ROWS / 128), blk, 0, stream>>>(xb, Wqkv_b, qkv_b, HH, QKV_LD);
  // 3) l2norm k,v in place
  l2norm_bf16<<<(2 * ROWS) / 4, blk, 0, stream>>>(qkv_b);
  // 4) per-chunk outer products (fp32 acc)
  outer_kernel<<<dim3(4, 4, NCHUNK), blk, 0, stream>>>(qkv_b, outer, scale);
  // 5) decay prefix scan
  prefix_kernel<<<(MM * MM) / 256, blk, 0, stream>>>(outer, M0, decay_c);
  // 6) retrieval -> r_b (bf16)
  retrieve_kernel<<<dim3(4, NCHUNK, BB), blk, 0, stream>>>(qkv_b, outer, r_b);
  // 7) output projection (bf16 MFMA): (16384x256)x(1024x256)^T -> fp32 out
  gemm_bt_mfma<0><<<dim3(HH / 128, ROWS / 128), blk, 0, stream>>>(r_b, Wo_b, out, MM, HH);
}

// Round 3
// 158.889 us; speedup vs baseline: 3.8589x; 1.2277x over previous
//
#include <hip/hip_runtime.h>
#include <math.h>

// Problem constants: B=4, S=4096, H=1024, M=256, chunk=64
#define BB 4
#define SS 4096
#define HH 1024
#define MM 256
#define CHUNK 64
#define NCHUNK 64
#define ROWS (BB*SS)          // 16384
#define QKV_LD 768
#define DECAY_F 0.99

typedef unsigned short u16;
typedef __attribute__((ext_vector_type(8))) short bf16x8;
typedef __attribute__((ext_vector_type(8))) unsigned short u16x8;
typedef __attribute__((ext_vector_type(4))) float f32x4;

__device__ inline u16 f2b(float f) {
  union { float f; unsigned u; } v; v.f = f;
  unsigned r = v.u + 0x7FFF + ((v.u >> 16) & 1);   // RNE
  return (u16)(r >> 16);
}
__device__ inline float b2f(u16 h) {
  union { unsigned u; float f; } v; v.u = ((unsigned)h) << 16; return v.f;
}

// async global->LDS, 16B per lane. LDS dest must be wave-uniform base
// (HW writes base + lane*16); global src is per-lane.
__device__ inline void gload16(const void* g, void* l) {
  __builtin_amdgcn_global_load_lds(
      (const __attribute__((address_space(1))) unsigned int*)g,
      (__attribute__((address_space(3))) unsigned int*)l, 16, 0, 0);
}

// ---------------------------------------------------------------------------
// fp32 -> bf16 cast of x, 4 elems/thread
// ---------------------------------------------------------------------------
__global__ __launch_bounds__(256) void cast_x_kernel(const float* __restrict__ src,
                                                     u16* __restrict__ dst) {
  int i = blockIdx.x * 256 + threadIdx.x;
  float4 v = reinterpret_cast<const float4*>(src)[i];
  ushort4 o;
  o.x = f2b(v.x); o.y = f2b(v.y); o.z = f2b(v.z); o.w = f2b(v.w);
  reinterpret_cast<ushort4*>(dst)[i] = o;
}

// all 4 weight casts in one launch; each weight is 256*1024 = 262144 elems
__global__ __launch_bounds__(256) void cast_w_kernel(const float* __restrict__ Wq,
                                                     const float* __restrict__ Wk,
                                                     const float* __restrict__ Wv,
                                                     const float* __restrict__ Wo,
                                                     u16* __restrict__ Wqkv_b,
                                                     u16* __restrict__ Wo_b) {
  int b = blockIdx.x, which = b >> 8;
  int i = ((b & 255) << 8) + threadIdx.x;     // float4 index in [0,65536)
  const float* src = which == 0 ? Wq : which == 1 ? Wk : which == 2 ? Wv : Wo;
  u16* dst = which < 3 ? Wqkv_b + which * (MM * HH) : Wo_b;
  float4 v = reinterpret_cast<const float4*>(src)[i];
  ushort4 o;
  o.x = f2b(v.x); o.y = f2b(v.y); o.z = f2b(v.z); o.w = f2b(v.w);
  reinterpret_cast<ushort4*>(dst)[i] = o;
}

// ---------------------------------------------------------------------------
// Unified 128x128 MFMA GEMM (C = A * B^T variants), global_load_lds staging
// into conflict-free fragment-major LDS (slot = mtile*64+lane, 16B/slot).
// 256 thr = 4 waves, each wave 64x64 (4x4 frags of mfma_f32_16x16x32_bf16).
// ---------------------------------------------------------------------------
#define M_STD_BF16 0   // C bf16 row-major ldc
#define M_STD_F32  1   // C fp32 row-major ldc
#define M_OUTER    2   // A=vT,B=kT (ld 16384), K per chunk t, C=outer[t] *scale
#define M_RETR     3   // A=q (ld 768, chunk rows), B=Mprev[t] fp32 reg-staged

template<int MODE>
__global__ __launch_bounds__(256) void gemm128(const u16* __restrict__ A,
                                               const u16* __restrict__ Bg,
                                               const float* __restrict__ Bf,
                                               void* __restrict__ Cv,
                                               int K, int lda, int ldb, int ldc,
                                               float scale) {
  __shared__ bf16x8 As[512];   // 8 KB
  __shared__ bf16x8 Bs[512];   // 8 KB
  const int tid = threadIdx.x, lane = tid & 63, wv = tid >> 6;
  const int wr = wv >> 1, wc = wv & 1;
  const int t = (MODE == M_OUTER || MODE == M_RETR) ? blockIdx.z : 0;
  const int row0 = blockIdx.y * 128;
  const int col0 = blockIdx.x * 128;
  const int NK = K >> 5;
  const float* Mt = (MODE == M_RETR) ? (Bf + (size_t)t * (MM * MM)) : nullptr;

  auto stage = [&](int ks) {
    int koff;
    if (MODE == M_OUTER) koff = ((ks >> 1) << 12) + t * CHUNK + ((ks & 1) << 5);
    else                 koff = ks << 5;
#pragma unroll
    for (int j = 0; j < 2; ++j) {
      int m = j * 4 + wv;                       // mtile 0..7 (wave-uniform)
      int rf = m * 16 + (lane & 15);            // fragment row in [0,128)
      size_t arow;
      if (MODE == M_RETR)
        arow = (size_t)(2 * blockIdx.y + (rf >> 6)) * SS + (size_t)t * CHUNK + (rf & 63);
      else
        arow = (size_t)(row0 + rf);
      const u16* ga = A + arow * (size_t)lda + koff + ((lane >> 4) << 3);
      gload16(ga, &As[m * 64]);
      if (MODE != M_RETR) {
        const u16* gb = Bg + (size_t)(col0 + rf) * ldb + koff + ((lane >> 4) << 3);
        gload16(gb, &Bs[m * 64]);
      }
    }
    if (MODE == M_RETR) {
      // B = Mprev[t] fp32 -> bf16 reg-staged into fragment-major slots
#pragma unroll
      for (int j = 0; j < 2; ++j) {
        int s = tid + j * 256;
        int n = (s >> 6) * 16 + (lane & 15);
        const float* gm = Mt + (size_t)(col0 + n) * MM + (ks << 5) + ((lane >> 4) << 3);
        float4 f0 = *reinterpret_cast<const float4*>(gm);
        float4 f1 = *reinterpret_cast<const float4*>(gm + 4);
        u16x8 h;
        h[0] = f2b(f0.x); h[1] = f2b(f0.y); h[2] = f2b(f0.z); h[3] = f2b(f0.w);
        h[4] = f2b(f1.x); h[5] = f2b(f1.y); h[6] = f2b(f1.z); h[7] = f2b(f1.w);
        *reinterpret_cast<u16x8*>(&Bs[s]) = h;
      }
    }
  };

  f32x4 acc[4][4] = {};
  stage(0);
  for (int ks = 0; ks < NK; ++ks) {
    __syncthreads();                            // staged data visible
    bf16x8 af[4], bfr[4];
#pragma unroll
    for (int m = 0; m < 4; ++m) af[m] = As[(wr * 4 + m) * 64 + lane];
#pragma unroll
    for (int n = 0; n < 4; ++n) bfr[n] = Bs[(wc * 4 + n) * 64 + lane];
#pragma unroll
    for (int m = 0; m < 4; ++m)
#pragma unroll
      for (int n = 0; n < 4; ++n)
        acc[m][n] = __builtin_amdgcn_mfma_f32_16x16x32_bf16(af[m], bfr[n], acc[m][n], 0, 0, 0);
    if (ks + 1 < NK) {
      __syncthreads();                          // frag reads done before overwrite
      stage(ks + 1);
    }
  }

  // C/D layout: col = lane&15, row = (lane>>4)*4 + reg
  const int r4 = (lane >> 4) << 2;
  const int cc = lane & 15;
#pragma unroll
  for (int m = 0; m < 4; ++m)
#pragma unroll
    for (int n = 0; n < 4; ++n)
#pragma unroll
      for (int r = 0; r < 4; ++r) {
        int lr = wr * 64 + m * 16 + r4 + r;
        int lc = wc * 64 + n * 16 + cc;
        float vv = acc[m][n][r];
        if (MODE == M_STD_BF16) {
          ((u16*)Cv)[(size_t)(row0 + lr) * ldc + col0 + lc] = f2b(vv);
        } else if (MODE == M_STD_F32) {
          ((float*)Cv)[(size_t)(row0 + lr) * ldc + col0 + lc] = vv;
        } else if (MODE == M_OUTER) {
          ((float*)Cv)[(size_t)t * (MM * MM) + (size_t)(row0 + lr) * MM + col0 + lc] = vv * scale;
        } else {  // M_RETR
          size_t rowg = (size_t)(2 * blockIdx.y + (lr >> 6)) * SS + (size_t)t * CHUNK + (lr & 63);
          ((u16*)Cv)[rowg * MM + col0 + lc] = f2b(vv);
        }
      }
}

// ---------------------------------------------------------------------------
// Fused l2norm + transpose: qkv cols [256,512)=k, [512,768)=v -> kT,vT
// [256][16384] bf16. Block = 64 rows; LDS transpose tile.
// ---------------------------------------------------------------------------
__global__ __launch_bounds__(256) void l2normT_kernel(const u16* __restrict__ qkv,
                                                      u16* __restrict__ kT,
                                                      u16* __restrict__ vT) {
  __shared__ u16 T[256][72];     // [col][row], pitch 72 u16 = 144B (16B mult)
  __shared__ float ps[64][4];
  __shared__ float inv[64];
  const int tid = threadIdx.x;
  const int q = tid >> 6, rl = tid & 63;   // wave index = col quarter, lane = row
  const int row0 = blockIdx.x * 64;
#pragma unroll 1
  for (int seg = 0; seg < 2; ++seg) {
    u16* dstT = seg ? vT : kT;
    const int segbase = 256 + seg * 256;
    float ss = 0.f;
#pragma unroll
    for (int i = 0; i < 8; ++i) {
      u16x8 v = *reinterpret_cast<const u16x8*>(
          qkv + (size_t)(row0 + rl) * QKV_LD + segbase + q * 64 + i * 8);
#pragma unroll
      for (int e = 0; e < 8; ++e) {
        float f = b2f(v[e]);
        ss += f * f;
        T[q * 64 + i * 8 + e][rl] = v[e];
      }
    }
    ps[rl][q] = ss;
    __syncthreads();
    if (tid < 64) {
      float s = ps[tid][0] + ps[tid][1] + ps[tid][2] + ps[tid][3];
      inv[tid] = 1.0f / fmaxf(sqrtf(s), 1e-12f);
    }
    __syncthreads();
    // write phase: lane handles (col, 8 rows); 16B coalesced global stores
#pragma unroll
    for (int p = 0; p < 8; ++p) {
      int c = p * 32 + q * 8 + (rl >> 3);
      int r0 = (rl & 7) * 8;
      u16x8 val = *reinterpret_cast<const u16x8*>(&T[c][r0]);
      u16x8 o;
#pragma unroll
      for (int e = 0; e < 8; ++e) o[e] = f2b(b2f(val[e]) * inv[r0 + e]);
      *reinterpret_cast<u16x8*>(dstT + (size_t)c * ROWS + row0 + r0) = o;
    }
    __syncthreads();   // T reused next segment
  }
}

// ---------------------------------------------------------------------------
// Decay prefix over t (in place: outer[t] <- Mprev[t]), depth-8 prefetch.
// ---------------------------------------------------------------------------
__global__ __launch_bounds__(256) void prefix_kernel(float* __restrict__ outer,
                                                     const float* __restrict__ M0,
                                                     float decay_c) {
  int ij = blockIdx.x * 256 + threadIdx.x;
  float run = M0[ij];
  float pre[8];
#pragma unroll
  for (int d = 0; d < 8; ++d) pre[d] = outer[(size_t)d * (MM * MM) + ij];
#pragma unroll 1
  for (int tb = 0; tb < NCHUNK; tb += 8) {
#pragma unroll
    for (int d = 0; d < 8; ++d) {
      int tc = tb + d;
      float o = pre[d];
      if (tb + 8 < NCHUNK) pre[d] = outer[(size_t)(tc + 8) * (MM * MM) + ij];
      outer[(size_t)tc * (MM * MM) + ij] = run;
      run = decay_c * run + o;
    }
  }
}

// ---------------------------------------------------------------------------
extern "C" void kernel_launch(void* const* d_in, const int* in_sizes, int n_in,
                              void* d_out, int out_size, void* d_ws, size_t ws_size,
                              hipStream_t stream) {
  const float* x  = (const float*)d_in[0];
  const float* Wq = (const float*)d_in[1];
  const float* Wk = (const float*)d_in[2];
  const float* Wv = (const float*)d_in[3];
  const float* Wo = (const float*)d_in[4];
  const float* M0 = (const float*)d_in[5];
  float* out = (float*)d_out;

  char* ws = (char*)d_ws;
  // [0,32M): xb (bf16 16384x1024); after QKV GEMM reused:
  //   kT @0 (8M), vT @8M (8M), outer fp32 @16M (16M); r_b @0 after outer
  u16*   xb     = (u16*)(ws);
  u16*   qkv_b  = (u16*)(ws + 33554432);    // 16384x768 bf16 (24M)
  u16*   Wqkv_b = (u16*)(ws + 58720256);    // 768x1024 bf16 (1.5M)
  u16*   Wo_b   = (u16*)(ws + 60293120);    // 1024x256 bf16 (0.5M)
  u16*   kT     = (u16*)(ws);               // 256x16384 bf16 (8M)
  u16*   vT     = (u16*)(ws + 8388608);     // 256x16384 bf16 (8M)
  float* outer  = (float*)(ws + 16777216);  // 64x256x256 fp32 (16M)
  u16*   r_b    = (u16*)(ws);               // 16384x256 bf16 (8M), over dead kT

  const float scale   = 1.0f / (BB * CHUNK);
  const float decay_c = (float)pow(DECAY_F, (double)CHUNK);
  dim3 blk(256);

  // 1) casts
  cast_x_kernel<<<(ROWS * HH / 4) / 256, blk, 0, stream>>>(x, xb);
  cast_w_kernel<<<1024, blk, 0, stream>>>(Wq, Wk, Wv, Wo, Wqkv_b, Wo_b);
  // 2) fused QKV projection: (16384x1024)x(768x1024)^T -> qkv_b
  gemm128<M_STD_BF16><<<dim3(QKV_LD / 128, ROWS / 128), blk, 0, stream>>>(
      xb, Wqkv_b, nullptr, qkv_b, HH, HH, HH, QKV_LD, 0.f);
  // 3) l2norm k,v + transpose -> kT, vT
  l2normT_kernel<<<ROWS / 64, blk, 0, stream>>>(qkv_b, kT, vT);
  // 4) per-chunk outer products: outer[t] = scale * vT_t * kT_t^T
  gemm128<M_OUTER><<<dim3(2, 2, NCHUNK), blk, 0, stream>>>(
      vT, kT, nullptr, outer, MM, ROWS, ROWS, MM, scale);
  // 5) decay prefix scan (in place)
  prefix_kernel<<<(MM * MM) / 256, blk, 0, stream>>>(outer, M0, decay_c);
  // 6) retrieval: r = q @ Mprev[t]^T -> r_b (bf16)
  gemm128<M_RETR><<<dim3(2, 2, NCHUNK), blk, 0, stream>>>(
      qkv_b, nullptr, outer, r_b, MM, QKV_LD, 0, MM, 0.f);
  // 7) output projection: (16384x256)x(1024x256)^T -> fp32 out
  gemm128<M_STD_F32><<<dim3(HH / 128, ROWS / 128), blk, 0, stream>>>(
      r_b, Wo_b, nullptr, out, MM, MM, MM, HH, 0.f);
}

// Round 4
// 157.105 us; speedup vs baseline: 3.9027x; 1.0114x over previous
//
#include <hip/hip_runtime.h>
#include <math.h>

// Problem constants: B=4, S=4096, H=1024, M=256, chunk=64
#define BB 4
#define SS 4096
#define HH 1024
#define MM 256
#define CHUNK 64
#define NCHUNK 64
#define ROWS (BB*SS)          // 16384
#define QKV_LD 768
#define DECAY_F 0.99

typedef unsigned short u16;
typedef __attribute__((ext_vector_type(8))) short bf16x8;
typedef __attribute__((ext_vector_type(8))) unsigned short u16x8;
typedef __attribute__((ext_vector_type(4))) float f32x4;

__device__ inline u16 f2b(float f) {
  union { float f; unsigned u; } v; v.f = f;
  unsigned r = v.u + 0x7FFF + ((v.u >> 16) & 1);   // RNE
  return (u16)(r >> 16);
}
__device__ inline float b2f(u16 h) {
  union { unsigned u; float f; } v; v.u = ((unsigned)h) << 16; return v.f;
}

// async global->LDS, 16B per lane. LDS dest wave-uniform base; global src per-lane.
__device__ inline void gload16(const void* g, void* l) {
  __builtin_amdgcn_global_load_lds(
      (const __attribute__((address_space(1))) unsigned int*)g,
      (__attribute__((address_space(3))) unsigned int*)l, 16, 0, 0);
}

// ---------------------------------------------------------------------------
// fp32 -> bf16 cast of x, 4 elems/thread
// ---------------------------------------------------------------------------
__global__ __launch_bounds__(256) void cast_x_kernel(const float* __restrict__ src,
                                                     u16* __restrict__ dst) {
  int i = blockIdx.x * 256 + threadIdx.x;
  float4 v = reinterpret_cast<const float4*>(src)[i];
  ushort4 o;
  o.x = f2b(v.x); o.y = f2b(v.y); o.z = f2b(v.z); o.w = f2b(v.w);
  reinterpret_cast<ushort4*>(dst)[i] = o;
}

// all 4 weight casts in one launch; each weight is 256*1024 elems
__global__ __launch_bounds__(256) void cast_w_kernel(const float* __restrict__ Wq,
                                                     const float* __restrict__ Wk,
                                                     const float* __restrict__ Wv,
                                                     const float* __restrict__ Wo,
                                                     u16* __restrict__ Wqkv_b,
                                                     u16* __restrict__ Wo_b) {
  int b = blockIdx.x, which = b >> 8;
  int i = ((b & 255) << 8) + threadIdx.x;
  const float* src = which == 0 ? Wq : which == 1 ? Wk : which == 2 ? Wv : Wo;
  u16* dst = which < 3 ? Wqkv_b + which * (MM * HH) : Wo_b;
  float4 v = reinterpret_cast<const float4*>(src)[i];
  ushort4 o;
  o.x = f2b(v.x); o.y = f2b(v.y); o.z = f2b(v.z); o.w = f2b(v.w);
  reinterpret_cast<ushort4*>(dst)[i] = o;
}

// ---------------------------------------------------------------------------
// Unified 128x128 MFMA GEMM, double-buffered LDS (2-phase pipeline), frag-
// major conflict-free LDS layout, gload_lds staging, XCD-chunked swizzle for
// the big modes. 256 thr = 4 waves, each wave 64x64 (4x4 frags, 16x16x32).
// ---------------------------------------------------------------------------
#define M_STD_BF16 0   // C bf16 row-major ldc
#define M_STD_F32  1   // C fp32 row-major ldc
#define M_OUTER    2   // A=vT,B=kT (ld 16384), K per chunk t, C=outer[t]*scale
#define M_RETR     3   // A=q (ld 768, chunk rows), B=Mprev[t] fp32 reg-staged

template<int MODE>
__global__ __launch_bounds__(256) void gemm128(const u16* __restrict__ A,
                                               const u16* __restrict__ Bg,
                                               const float* __restrict__ Bf,
                                               void* __restrict__ Cv,
                                               int K, int lda, int ldb, int ldc,
                                               float scale) {
  __shared__ bf16x8 As[2][512];   // 2 x 8 KB
  __shared__ bf16x8 Bs[2][512];   // 2 x 8 KB
  const int tid = threadIdx.x, lane = tid & 63, wv = tid >> 6;
  const int wr = wv >> 1, wc = wv & 1;
  const int t = (MODE == M_OUTER || MODE == M_RETR) ? blockIdx.z : 0;

  // XCD-chunked bijective swizzle for the big GEMMs (nwg % 8 == 0)
  int bx, by;
  if (MODE == M_STD_BF16 || MODE == M_STD_F32) {
    int gx = gridDim.x;
    int nwg = gx * gridDim.y;
    int lin = blockIdx.y * gx + blockIdx.x;
    int chunk = nwg >> 3;
    int orig = (lin & 7) * chunk + (lin >> 3);
    bx = orig % gx; by = orig / gx;
  } else { bx = blockIdx.x; by = blockIdx.y; }

  const int row0 = by * 128;
  const int col0 = bx * 128;
  const int NK = K >> 5;
  const float* Mt = (MODE == M_RETR) ? (Bf + (size_t)t * (MM * MM)) : nullptr;

  auto stage = [&](int ks, int buf) {
    int koff;
    if (MODE == M_OUTER) koff = ((ks >> 1) << 12) + t * CHUNK + ((ks & 1) << 5);
    else                 koff = ks << 5;
#pragma unroll
    for (int j = 0; j < 2; ++j) {
      int m = j * 4 + wv;                       // mtile 0..7 (wave-uniform)
      int rf = m * 16 + (lane & 15);            // fragment row in [0,128)
      size_t arow;
      if (MODE == M_RETR)
        arow = (size_t)(2 * by + (rf >> 6)) * SS + (size_t)t * CHUNK + (rf & 63);
      else
        arow = (size_t)(row0 + rf);
      const u16* ga = A + arow * (size_t)lda + koff + ((lane >> 4) << 3);
      gload16(ga, &As[buf][m * 64]);
      if (MODE != M_RETR) {
        const u16* gb = Bg + (size_t)(col0 + rf) * ldb + koff + ((lane >> 4) << 3);
        gload16(gb, &Bs[buf][m * 64]);
      }
    }
    if (MODE == M_RETR) {
      // B = Mprev[t] fp32 -> bf16 reg-staged into fragment-major slots
#pragma unroll
      for (int j = 0; j < 2; ++j) {
        int s = tid + j * 256;
        int n = (s >> 6) * 16 + (lane & 15);
        const float* gm = Mt + (size_t)(col0 + n) * MM + (ks << 5) + ((lane >> 4) << 3);
        float4 f0 = *reinterpret_cast<const float4*>(gm);
        float4 f1 = *reinterpret_cast<const float4*>(gm + 4);
        u16x8 h;
        h[0] = f2b(f0.x); h[1] = f2b(f0.y); h[2] = f2b(f0.z); h[3] = f2b(f0.w);
        h[4] = f2b(f1.x); h[5] = f2b(f1.y); h[6] = f2b(f1.z); h[7] = f2b(f1.w);
        *reinterpret_cast<u16x8*>(&Bs[buf][s]) = h;
      }
    }
  };

  f32x4 acc[4][4] = {};
  stage(0, 0);
  for (int ks = 0; ks < NK; ++ks) {
    __syncthreads();                 // buf[ks&1] staged; prev frag reads done
    if (ks + 1 < NK) stage(ks + 1, (ks + 1) & 1);   // overlap w/ compute below
    const int buf = ks & 1;
    bf16x8 af[4], bfr[4];
#pragma unroll
    for (int m = 0; m < 4; ++m) af[m] = As[buf][(wr * 4 + m) * 64 + lane];
#pragma unroll
    for (int n = 0; n < 4; ++n) bfr[n] = Bs[buf][(wc * 4 + n) * 64 + lane];
#pragma unroll
    for (int m = 0; m < 4; ++m)
#pragma unroll
      for (int n = 0; n < 4; ++n)
        acc[m][n] = __builtin_amdgcn_mfma_f32_16x16x32_bf16(af[m], bfr[n], acc[m][n], 0, 0, 0);
  }

  // C/D layout: col = lane&15, row = (lane>>4)*4 + reg
  const int r4 = (lane >> 4) << 2;
  const int cc = lane & 15;
#pragma unroll
  for (int m = 0; m < 4; ++m)
#pragma unroll
    for (int n = 0; n < 4; ++n)
#pragma unroll
      for (int r = 0; r < 4; ++r) {
        int lr = wr * 64 + m * 16 + r4 + r;
        int lc = wc * 64 + n * 16 + cc;
        float vv = acc[m][n][r];
        if (MODE == M_STD_BF16) {
          ((u16*)Cv)[(size_t)(row0 + lr) * ldc + col0 + lc] = f2b(vv);
        } else if (MODE == M_STD_F32) {
          ((float*)Cv)[(size_t)(row0 + lr) * ldc + col0 + lc] = vv;
        } else if (MODE == M_OUTER) {
          ((float*)Cv)[(size_t)t * (MM * MM) + (size_t)(row0 + lr) * MM + col0 + lc] = vv * scale;
        } else {  // M_RETR
          size_t rowg = (size_t)(2 * by + (lr >> 6)) * SS + (size_t)t * CHUNK + (lr & 63);
          ((u16*)Cv)[rowg * MM + col0 + lc] = f2b(vv);
        }
      }
}

// ---------------------------------------------------------------------------
// Fused l2norm + transpose: qkv cols [256,512)=k, [512,768)=v -> kT,vT
// [256][16384] bf16. Block = 64 rows; LDS transpose tile.
// ---------------------------------------------------------------------------
__global__ __launch_bounds__(256) void l2normT_kernel(const u16* __restrict__ qkv,
                                                      u16* __restrict__ kT,
                                                      u16* __restrict__ vT) {
  __shared__ u16 T[256][72];
  __shared__ float ps[64][4];
  __shared__ float inv[64];
  const int tid = threadIdx.x;
  const int q = tid >> 6, rl = tid & 63;
  const int row0 = blockIdx.x * 64;
#pragma unroll 1
  for (int seg = 0; seg < 2; ++seg) {
    u16* dstT = seg ? vT : kT;
    const int segbase = 256 + seg * 256;
    float ss = 0.f;
#pragma unroll
    for (int i = 0; i < 8; ++i) {
      u16x8 v = *reinterpret_cast<const u16x8*>(
          qkv + (size_t)(row0 + rl) * QKV_LD + segbase + q * 64 + i * 8);
#pragma unroll
      for (int e = 0; e < 8; ++e) {
        float f = b2f(v[e]);
        ss += f * f;
        T[q * 64 + i * 8 + e][rl] = v[e];
      }
    }
    ps[rl][q] = ss;
    __syncthreads();
    if (tid < 64) {
      float s = ps[tid][0] + ps[tid][1] + ps[tid][2] + ps[tid][3];
      inv[tid] = 1.0f / fmaxf(sqrtf(s), 1e-12f);
    }
    __syncthreads();
#pragma unroll
    for (int p = 0; p < 8; ++p) {
      int c = p * 32 + q * 8 + (rl >> 3);
      int r0 = (rl & 7) * 8;
      u16x8 val = *reinterpret_cast<const u16x8*>(&T[c][r0]);
      u16x8 o;
#pragma unroll
      for (int e = 0; e < 8; ++e) o[e] = f2b(b2f(val[e]) * inv[r0 + e]);
      *reinterpret_cast<u16x8*>(dstT + (size_t)c * ROWS + row0 + r0) = o;
    }
    __syncthreads();
  }
}

// ---------------------------------------------------------------------------
// Decay prefix over t (in place: outer[t] <- Mprev[t]), depth-8 prefetch.
// ---------------------------------------------------------------------------
__global__ __launch_bounds__(256) void prefix_kernel(float* __restrict__ outer,
                                                     const float* __restrict__ M0,
                                                     float decay_c) {
  int ij = blockIdx.x * 256 + threadIdx.x;
  float run = M0[ij];
  float pre[8];
#pragma unroll
  for (int d = 0; d < 8; ++d) pre[d] = outer[(size_t)d * (MM * MM) + ij];
#pragma unroll 1
  for (int tb = 0; tb < NCHUNK; tb += 8) {
#pragma unroll
    for (int d = 0; d < 8; ++d) {
      int tc = tb + d;
      float o = pre[d];
      if (tb + 8 < NCHUNK) pre[d] = outer[(size_t)(tc + 8) * (MM * MM) + ij];
      outer[(size_t)tc * (MM * MM) + ij] = run;
      run = decay_c * run + o;
    }
  }
}

// ---------------------------------------------------------------------------
extern "C" void kernel_launch(void* const* d_in, const int* in_sizes, int n_in,
                              void* d_out, int out_size, void* d_ws, size_t ws_size,
                              hipStream_t stream) {
  const float* x  = (const float*)d_in[0];
  const float* Wq = (const float*)d_in[1];
  const float* Wk = (const float*)d_in[2];
  const float* Wv = (const float*)d_in[3];
  const float* Wo = (const float*)d_in[4];
  const float* M0 = (const float*)d_in[5];
  float* out = (float*)d_out;

  char* ws = (char*)d_ws;
  u16*   xb     = (u16*)(ws);               // 16384x1024 bf16 (32M)
  u16*   qkv_b  = (u16*)(ws + 33554432);    // 16384x768 bf16 (24M)
  u16*   Wqkv_b = (u16*)(ws + 58720256);    // 768x1024 bf16 (1.5M)
  u16*   Wo_b   = (u16*)(ws + 60293120);    // 1024x256 bf16 (0.5M)
  u16*   kT     = (u16*)(ws);               // 256x16384 bf16 (8M)
  u16*   vT     = (u16*)(ws + 8388608);     // 256x16384 bf16 (8M)
  float* outer  = (float*)(ws + 16777216);  // 64x256x256 fp32 (16M)
  u16*   r_b    = (u16*)(ws);               // 16384x256 bf16 (8M), over dead kT

  const float scale   = 1.0f / (BB * CHUNK);
  const float decay_c = (float)pow(DECAY_F, (double)CHUNK);
  dim3 blk(256);

  // 1) casts
  cast_x_kernel<<<(ROWS * HH / 4) / 256, blk, 0, stream>>>(x, xb);
  cast_w_kernel<<<1024, blk, 0, stream>>>(Wq, Wk, Wv, Wo, Wqkv_b, Wo_b);
  // 2) fused QKV projection: (16384x1024)x(768x1024)^T -> qkv_b
  gemm128<M_STD_BF16><<<dim3(QKV_LD / 128, ROWS / 128), blk, 0, stream>>>(
      xb, Wqkv_b, nullptr, qkv_b, HH, HH, HH, QKV_LD, 0.f);
  // 3) l2norm k,v + transpose -> kT, vT
  l2normT_kernel<<<ROWS / 64, blk, 0, stream>>>(qkv_b, kT, vT);
  // 4) per-chunk outer products: outer[t] = scale * vT_t * kT_t^T
  gemm128<M_OUTER><<<dim3(2, 2, NCHUNK), blk, 0, stream>>>(
      vT, kT, nullptr, outer, MM, ROWS, ROWS, MM, scale);
  // 5) decay prefix scan (in place)
  prefix_kernel<<<(MM * MM) / 256, blk, 0, stream>>>(outer, M0, decay_c);
  // 6) retrieval: r = q @ Mprev[t]^T -> r_b (bf16)
  gemm128<M_RETR><<<dim3(2, 2, NCHUNK), blk, 0, stream>>>(
      qkv_b, nullptr, outer, r_b, MM, QKV_LD, 0, MM, 0.f);
  // 7) output projection: (16384x256)x(1024x256)^T -> fp32 out
  gemm128<M_STD_F32><<<dim3(HH / 128, ROWS / 128), blk, 0, stream>>>(
      r_b, Wo_b, nullptr, out, MM, MM, MM, HH, 0.f);
}

// Round 5
// 153.208 us; speedup vs baseline: 4.0020x; 1.0254x over previous
//
#include <hip/hip_runtime.h>
#include <math.h>

// Problem constants: B=4, S=4096, H=1024, M=256, chunk=64
#define BB 4
#define SS 4096
#define HH 1024
#define MM 256
#define CHUNK 64
#define NCHUNK 64
#define ROWS (BB*SS)          // 16384
#define QKV_LD 768
#define DECAY_F 0.99

typedef unsigned short u16;
typedef __attribute__((ext_vector_type(8))) short bf16x8;
typedef __attribute__((ext_vector_type(8))) unsigned short u16x8;
typedef __attribute__((ext_vector_type(4))) float f32x4;

__device__ inline u16 f2b(float f) {
  union { float f; unsigned u; } v; v.f = f;
  unsigned r = v.u + 0x7FFF + ((v.u >> 16) & 1);   // RNE
  return (u16)(r >> 16);
}
__device__ inline float b2f(u16 h) {
  union { unsigned u; float f; } v; v.u = ((unsigned)h) << 16; return v.f;
}

// async global->LDS, 16B per lane. LDS dest wave-uniform base; global src per-lane.
__device__ inline void gload16(const void* g, void* l) {
  __builtin_amdgcn_global_load_lds(
      (const __attribute__((address_space(1))) unsigned int*)g,
      (__attribute__((address_space(3))) unsigned int*)l, 16, 0, 0);
}

// ---------------------------------------------------------------------------
// fp32 -> bf16 cast of x, 4 elems/thread
// ---------------------------------------------------------------------------
__global__ __launch_bounds__(256) void cast_x_kernel(const float* __restrict__ src,
                                                     u16* __restrict__ dst) {
  int i = blockIdx.x * 256 + threadIdx.x;
  float4 v = reinterpret_cast<const float4*>(src)[i];
  ushort4 o;
  o.x = f2b(v.x); o.y = f2b(v.y); o.z = f2b(v.z); o.w = f2b(v.w);
  reinterpret_cast<ushort4*>(dst)[i] = o;
}

// all 4 weight casts in one launch; each weight is 256*1024 elems
__global__ __launch_bounds__(256) void cast_w_kernel(const float* __restrict__ Wq,
                                                     const float* __restrict__ Wk,
                                                     const float* __restrict__ Wv,
                                                     const float* __restrict__ Wo,
                                                     u16* __restrict__ Wqkv_b,
                                                     u16* __restrict__ Wo_b) {
  int b = blockIdx.x, which = b >> 8;
  int i = ((b & 255) << 8) + threadIdx.x;
  const float* src = which == 0 ? Wq : which == 1 ? Wk : which == 2 ? Wv : Wo;
  u16* dst = which < 3 ? Wqkv_b + which * (MM * HH) : Wo_b;
  float4 v = reinterpret_cast<const float4*>(src)[i];
  ushort4 o;
  o.x = f2b(v.x); o.y = f2b(v.y); o.z = f2b(v.z); o.w = f2b(v.w);
  reinterpret_cast<ushort4*>(dst)[i] = o;
}

// ---------------------------------------------------------------------------
// Unified 128x128 MFMA GEMM, depth-3 LDS pipeline with counted vmcnt (T3+T4),
// frag-major conflict-free LDS, gload_lds staging for BOTH operands, XCD
// swizzle for big modes. 256 thr = 4 waves, each wave 64x64 (4x4 frags).
// Pipeline: prologue stage(0),stage(1); per iter: wait vmcnt(4) [oldest stage
// done], raw s_barrier, issue stage(ks+2), ds_read buf[ks%3], 16 MFMA.
// ---------------------------------------------------------------------------
#define M_STD_BF16 0   // C bf16 row-major ldc
#define M_STD_F32  1   // C fp32 row-major ldc
#define M_OUTER    2   // A=vT,B=kT (ld 16384), K per chunk t, C=outer[t]*scale
#define M_RETR     3   // A=q (ld 768, chunk rows), B=Mprev_b[t] bf16 (ld 256)

template<int MODE>
__global__ __launch_bounds__(256) void gemm128(const u16* __restrict__ A,
                                               const u16* __restrict__ Bg,
                                               void* __restrict__ Cv,
                                               int K, int lda, int ldb, int ldc,
                                               float scale) {
  __shared__ bf16x8 As[3][512];   // 3 x 8 KB
  __shared__ bf16x8 Bs[3][512];   // 3 x 8 KB
  const int tid = threadIdx.x, lane = tid & 63, wv = tid >> 6;
  const int wr = wv >> 1, wc = wv & 1;
  const int t = (MODE == M_OUTER || MODE == M_RETR) ? blockIdx.z : 0;

  // XCD-chunked bijective swizzle for the big GEMMs (nwg % 8 == 0)
  int bx, by;
  if (MODE == M_STD_BF16 || MODE == M_STD_F32) {
    int gx = gridDim.x;
    int nwg = gx * gridDim.y;
    int lin = blockIdx.y * gx + blockIdx.x;
    int chunk = nwg >> 3;
    int orig = (lin & 7) * chunk + (lin >> 3);
    bx = orig % gx; by = orig / gx;
  } else { bx = blockIdx.x; by = blockIdx.y; }

  const int row0 = by * 128;
  const int col0 = bx * 128;
  const int NK = K >> 5;
  const u16* Bbase = (MODE == M_RETR) ? (Bg + (size_t)t * (MM * MM)) : Bg;

  auto stage = [&](int ks, int buf) {
    int koff;
    if (MODE == M_OUTER) koff = ((ks >> 1) << 12) + t * CHUNK + ((ks & 1) << 5);
    else                 koff = ks << 5;
#pragma unroll
    for (int j = 0; j < 2; ++j) {
      int m = j * 4 + wv;                       // mtile 0..7 (wave-uniform)
      int rf = m * 16 + (lane & 15);            // fragment row in [0,128)
      size_t arow;
      if (MODE == M_RETR)
        arow = (size_t)(2 * by + (rf >> 6)) * SS + (size_t)t * CHUNK + (rf & 63);
      else
        arow = (size_t)(row0 + rf);
      const u16* ga = A + arow * (size_t)lda + koff + ((lane >> 4) << 3);
      gload16(ga, &As[buf][m * 64]);
      const u16* gb = Bbase + (size_t)(col0 + rf) * ldb + koff + ((lane >> 4) << 3);
      gload16(gb, &Bs[buf][m * 64]);
    }
  };

  f32x4 acc[4][4] = {};
  stage(0, 0);
  stage(1, 1);
  int rb = 0, sb = 2;
  for (int ks = 0; ks < NK; ++ks) {
    // counted drain: 2 stages (8 loads) in flight; wait for oldest 4.
    if (ks + 1 < NK) asm volatile("s_waitcnt vmcnt(4)" ::: "memory");
    else             asm volatile("s_waitcnt vmcnt(0)" ::: "memory");
    __builtin_amdgcn_s_barrier();           // all waves' stage(ks) visible
    if (ks + 2 < NK) stage(ks + 2, sb);     // issue early, lands >=1 iter later
    bf16x8 af[4], bfr[4];
#pragma unroll
    for (int m = 0; m < 4; ++m) af[m] = As[rb][(wr * 4 + m) * 64 + lane];
#pragma unroll
    for (int n = 0; n < 4; ++n) bfr[n] = Bs[rb][(wc * 4 + n) * 64 + lane];
#pragma unroll
    for (int m = 0; m < 4; ++m)
#pragma unroll
      for (int n = 0; n < 4; ++n)
        acc[m][n] = __builtin_amdgcn_mfma_f32_16x16x32_bf16(af[m], bfr[n], acc[m][n], 0, 0, 0);
    rb = (rb == 2) ? 0 : rb + 1;
    sb = (sb == 2) ? 0 : sb + 1;
  }

  // C/D layout: col = lane&15, row = (lane>>4)*4 + reg
  const int r4 = (lane >> 4) << 2;
  const int cc = lane & 15;
#pragma unroll
  for (int m = 0; m < 4; ++m)
#pragma unroll
    for (int n = 0; n < 4; ++n)
#pragma unroll
      for (int r = 0; r < 4; ++r) {
        int lr = wr * 64 + m * 16 + r4 + r;
        int lc = wc * 64 + n * 16 + cc;
        float vv = acc[m][n][r];
        if (MODE == M_STD_BF16) {
          ((u16*)Cv)[(size_t)(row0 + lr) * ldc + col0 + lc] = f2b(vv);
        } else if (MODE == M_STD_F32) {
          ((float*)Cv)[(size_t)(row0 + lr) * ldc + col0 + lc] = vv;
        } else if (MODE == M_OUTER) {
          ((float*)Cv)[(size_t)t * (MM * MM) + (size_t)(row0 + lr) * MM + col0 + lc] = vv * scale;
        } else {  // M_RETR
          size_t rowg = (size_t)(2 * by + (lr >> 6)) * SS + (size_t)t * CHUNK + (lr & 63);
          ((u16*)Cv)[rowg * MM + col0 + lc] = f2b(vv);
        }
      }
}

// ---------------------------------------------------------------------------
// Fused l2norm + transpose: qkv cols [256,512)=k, [512,768)=v -> kT,vT
// [256][16384] bf16. Block = 64 rows; LDS transpose tile.
// ---------------------------------------------------------------------------
__global__ __launch_bounds__(256) void l2normT_kernel(const u16* __restrict__ qkv,
                                                      u16* __restrict__ kT,
                                                      u16* __restrict__ vT) {
  __shared__ u16 T[256][72];
  __shared__ float ps[64][4];
  __shared__ float inv[64];
  const int tid = threadIdx.x;
  const int q = tid >> 6, rl = tid & 63;
  const int row0 = blockIdx.x * 64;
#pragma unroll 1
  for (int seg = 0; seg < 2; ++seg) {
    u16* dstT = seg ? vT : kT;
    const int segbase = 256 + seg * 256;
    float ss = 0.f;
#pragma unroll
    for (int i = 0; i < 8; ++i) {
      u16x8 v = *reinterpret_cast<const u16x8*>(
          qkv + (size_t)(row0 + rl) * QKV_LD + segbase + q * 64 + i * 8);
#pragma unroll
      for (int e = 0; e < 8; ++e) {
        float f = b2f(v[e]);
        ss += f * f;
        T[q * 64 + i * 8 + e][rl] = v[e];
      }
    }
    ps[rl][q] = ss;
    __syncthreads();
    if (tid < 64) {
      float s = ps[tid][0] + ps[tid][1] + ps[tid][2] + ps[tid][3];
      inv[tid] = 1.0f / fmaxf(sqrtf(s), 1e-12f);
    }
    __syncthreads();
#pragma unroll
    for (int p = 0; p < 8; ++p) {
      int c = p * 32 + q * 8 + (rl >> 3);
      int r0 = (rl & 7) * 8;
      u16x8 val = *reinterpret_cast<const u16x8*>(&T[c][r0]);
      u16x8 o;
#pragma unroll
      for (int e = 0; e < 8; ++e) o[e] = f2b(b2f(val[e]) * inv[r0 + e]);
      *reinterpret_cast<u16x8*>(dstT + (size_t)c * ROWS + row0 + r0) = o;
    }
    __syncthreads();
  }
}

// ---------------------------------------------------------------------------
// Decay prefix over t: Mprev_b[t] = bf16(run); run = decay*run + outer[t].
// outer read-only fp32; Mprev written bf16 (ready for gload_lds in RETR).
// ---------------------------------------------------------------------------
__global__ __launch_bounds__(256) void prefix_kernel(const float* __restrict__ outer,
                                                     const float* __restrict__ M0,
                                                     u16* __restrict__ Mprev_b,
                                                     float decay_c) {
  int ij = blockIdx.x * 256 + threadIdx.x;
  float run = M0[ij];
  float pre[8];
#pragma unroll
  for (int d = 0; d < 8; ++d) pre[d] = outer[(size_t)d * (MM * MM) + ij];
#pragma unroll 1
  for (int tb = 0; tb < NCHUNK; tb += 8) {
#pragma unroll
    for (int d = 0; d < 8; ++d) {
      int tc = tb + d;
      float o = pre[d];
      if (tb + 8 < NCHUNK) pre[d] = outer[(size_t)(tc + 8) * (MM * MM) + ij];
      Mprev_b[(size_t)tc * (MM * MM) + ij] = f2b(run);
      run = decay_c * run + o;
    }
  }
}

// ---------------------------------------------------------------------------
extern "C" void kernel_launch(void* const* d_in, const int* in_sizes, int n_in,
                              void* d_out, int out_size, void* d_ws, size_t ws_size,
                              hipStream_t stream) {
  const float* x  = (const float*)d_in[0];
  const float* Wq = (const float*)d_in[1];
  const float* Wk = (const float*)d_in[2];
  const float* Wv = (const float*)d_in[3];
  const float* Wo = (const float*)d_in[4];
  const float* M0 = (const float*)d_in[5];
  float* out = (float*)d_out;

  char* ws = (char*)d_ws;
  u16*   xb      = (u16*)(ws);               // 16384x1024 bf16 (32M)
  u16*   qkv_b   = (u16*)(ws + 33554432);    // 16384x768 bf16 (24M)
  u16*   Wqkv_b  = (u16*)(ws + 58720256);    // 768x1024 bf16 (1.5M)
  u16*   Wo_b    = (u16*)(ws + 60293120);    // 1024x256 bf16 (0.5M)
  u16*   kT      = (u16*)(ws);               // 256x16384 bf16 (8M), over dead xb
  u16*   vT      = (u16*)(ws + 8388608);     // 256x16384 bf16 (8M)
  float* outer   = (float*)(ws + 16777216);  // 64x256x256 fp32 (16M)
  u16*   Mprev_b = (u16*)(ws + 8388608);     // 64x256x256 bf16 (8M), over dead vT
  u16*   r_b     = (u16*)(ws);               // 16384x256 bf16 (8M), over dead kT

  const float scale   = 1.0f / (BB * CHUNK);
  const float decay_c = (float)pow(DECAY_F, (double)CHUNK);
  dim3 blk(256);

  // 1) casts
  cast_x_kernel<<<(ROWS * HH / 4) / 256, blk, 0, stream>>>(x, xb);
  cast_w_kernel<<<1024, blk, 0, stream>>>(Wq, Wk, Wv, Wo, Wqkv_b, Wo_b);
  // 2) fused QKV projection: (16384x1024)x(768x1024)^T -> qkv_b
  gemm128<M_STD_BF16><<<dim3(QKV_LD / 128, ROWS / 128), blk, 0, stream>>>(
      xb, Wqkv_b, qkv_b, HH, HH, HH, QKV_LD, 0.f);
  // 3) l2norm k,v + transpose -> kT, vT
  l2normT_kernel<<<ROWS / 64, blk, 0, stream>>>(qkv_b, kT, vT);
  // 4) per-chunk outer products: outer[t] = scale * vT_t * kT_t^T
  gemm128<M_OUTER><<<dim3(2, 2, NCHUNK), blk, 0, stream>>>(
      vT, kT, outer, MM, ROWS, ROWS, MM, scale);
  // 5) decay prefix scan -> Mprev_b (bf16)
  prefix_kernel<<<(MM * MM) / 256, blk, 0, stream>>>(outer, M0, Mprev_b, decay_c);
  // 6) retrieval: r = q @ Mprev_b[t]^T -> r_b (bf16)
  gemm128<M_RETR><<<dim3(2, 2, NCHUNK), blk, 0, stream>>>(
      qkv_b, Mprev_b, r_b, MM, QKV_LD, MM, MM, 0.f);
  // 7) output projection: (16384x256)x(1024x256)^T -> fp32 out
  gemm128<M_STD_F32><<<dim3(HH / 128, ROWS / 128), blk, 0, stream>>>(
      r_b, Wo_b, out, MM, MM, MM, HH, 0.f);
}

// Round 6
// 150.326 us; speedup vs baseline: 4.0787x; 1.0192x over previous
//
#include <hip/hip_runtime.h>
#include <math.h>

// Problem constants: B=4, S=4096, H=1024, M=256, chunk=64
#define BB 4
#define SS 4096
#define HH 1024
#define MM 256
#define CHUNK 64
#define NCHUNK 64
#define ROWS (BB*SS)          // 16384
#define QKV_LD 768
#define DECAY_F 0.99

typedef unsigned short u16;
typedef __attribute__((ext_vector_type(8))) short bf16x8;
typedef __attribute__((ext_vector_type(8))) unsigned short u16x8;
typedef __attribute__((ext_vector_type(4))) float f32x4;

__device__ inline u16 f2b(float f) {
  union { float f; unsigned u; } v; v.f = f;
  unsigned r = v.u + 0x7FFF + ((v.u >> 16) & 1);   // RNE
  return (u16)(r >> 16);
}
__device__ inline float b2f(u16 h) {
  union { unsigned u; float f; } v; v.u = ((unsigned)h) << 16; return v.f;
}

// all 4 weight casts in one launch; each weight is 256*1024 elems
__global__ __launch_bounds__(256) void cast_w_kernel(const float* __restrict__ Wq,
                                                     const float* __restrict__ Wk,
                                                     const float* __restrict__ Wv,
                                                     const float* __restrict__ Wo,
                                                     u16* __restrict__ Wqkv_b,
                                                     u16* __restrict__ Wo_b) {
  int b = blockIdx.x, which = b >> 8;
  int i = ((b & 255) << 8) + threadIdx.x;
  const float* src = which == 0 ? Wq : which == 1 ? Wk : which == 2 ? Wv : Wo;
  u16* dst = which < 3 ? Wqkv_b + which * (MM * HH) : Wo_b;
  float4 v = reinterpret_cast<const float4*>(src)[i];
  ushort4 o;
  o.x = f2b(v.x); o.y = f2b(v.y); o.z = f2b(v.z); o.w = f2b(v.w);
  reinterpret_cast<ushort4*>(dst)[i] = o;
}

// ---------------------------------------------------------------------------
// Unified 128x128 MFMA GEMM v2: 512 thr = 8 waves (2x4), reg-staged pipeline
// (loads issued 2 K-steps early; ds_write just before the consuming barrier),
// 2 LDS buffers, fragment-major slot=tid layout (contiguous 1KB ds r/w).
// Wave w: rows [(w>>2)*64,+64) x cols [(w&3)*32,+32): 4x2 frags, 8 MFMA/step.
// ---------------------------------------------------------------------------
#define M_QKV   0   // A = x fp32 (lda 1024, cast in-stage), C bf16 ldc 768
#define M_OUT   1   // A = r_b bf16 (lda 256), C fp32 ldc 1024
#define M_OUTER 2   // A=vT,B=kT (ld 16384), K=256 per chunk t, C=outer[t]*scale
#define M_RETR  3   // A=q (qkv ld 768, chunk rows), B=Mprev_b[t], C=r_b bf16

template<int MODE>
__global__ __launch_bounds__(512, 4) void gemm_v2(const void* __restrict__ Ap,
                                                  const u16* __restrict__ Bp,
                                                  void* __restrict__ Cv,
                                                  float scale) {
  constexpr int NK = (MODE == M_QKV) ? 32 : 8;
  __shared__ bf16x8 As[2][512];   // 2 x 8 KB
  __shared__ bf16x8 Bs[2][512];   // 2 x 8 KB
  const int tid = threadIdx.x, lane = tid & 63, wv = tid >> 6;
  const int wr = wv >> 2, wc = wv & 3;
  const int t64 = (MODE == M_OUTER || MODE == M_RETR) ? blockIdx.z : 0;

  // XCD-chunked bijective swizzle for the big GEMMs (nwg % 8 == 0)
  int bx, by;
  if (MODE == M_QKV || MODE == M_OUT) {
    int gx = gridDim.x;
    int nwg = gx * gridDim.y;
    int lin = blockIdx.y * gx + blockIdx.x;
    int chunk = nwg >> 3;
    int orig = (lin & 7) * chunk + (lin >> 3);
    bx = orig % gx; by = orig / gx;
  } else { bx = blockIdx.x; by = blockIdx.y; }

  const int row0 = by * 128;
  const int col0 = bx * 128;
  // staging coords: thread t owns LDS slot t = (mtile=t>>6, rowin=t&15, kgrp=(t>>4)&3)
  const int ar  = ((tid >> 6) << 4) | (tid & 15);   // row/col within tile [0,128)
  const int kof = ((tid >> 4) & 3) << 3;            // k offset within BK=32

  auto aoff = [&](int ks) -> size_t {
    if (MODE == M_QKV)  return (size_t)(row0 + ar) * HH + ks * 32 + kof;
    if (MODE == M_OUT)  return (size_t)(row0 + ar) * MM + ks * 32 + kof;
    if (MODE == M_OUTER) return (size_t)(row0 + ar) * ROWS + (ks >> 1) * SS +
                                t64 * CHUNK + ((ks & 1) << 5) + kof;
    /* M_RETR */ return ((size_t)(2 * by + (ar >> 6)) * SS + t64 * CHUNK + (ar & 63)) * QKV_LD +
                        ks * 32 + kof;
  };
  auto boff = [&](int ks) -> size_t {
    if (MODE == M_QKV)  return (size_t)(col0 + ar) * HH + ks * 32 + kof;
    if (MODE == M_OUT)  return (size_t)(col0 + ar) * MM + ks * 32 + kof;
    if (MODE == M_OUTER) return (size_t)(col0 + ar) * ROWS + (ks >> 1) * SS +
                                t64 * CHUNK + ((ks & 1) << 5) + kof;
    /* M_RETR */ return (size_t)t64 * (MM * MM) + (size_t)(col0 + ar) * MM + ks * 32 + kof;
  };

  // register staging sets (static indexing only — rule #20)
  float4 fA0a, fA0b, fA1a, fA1b;      // QKV fp32 A
  u16x8 rA0, rA1, rB0, rB1;

  auto loadA = [&](int ks, int p) {
    if (MODE == M_QKV) {
      const float* pa = (const float*)Ap + aoff(ks);
      if (p == 0) { fA0a = *(const float4*)pa; fA0b = *(const float4*)(pa + 4); }
      else        { fA1a = *(const float4*)pa; fA1b = *(const float4*)(pa + 4); }
    } else {
      const u16* pa = (const u16*)Ap + aoff(ks);
      if (p == 0) rA0 = *(const u16x8*)pa; else rA1 = *(const u16x8*)pa;
    }
  };
  auto loadB = [&](int ks, int p) {
    const u16* pb = Bp + boff(ks);
    if (p == 0) rB0 = *(const u16x8*)pb; else rB1 = *(const u16x8*)pb;
  };
  auto writeLDS = [&](int buf, int p) {
    u16x8 ha;
    if (MODE == M_QKV) {
      float4 fa = p ? fA1a : fA0a, fb = p ? fA1b : fA0b;
      ha[0] = f2b(fa.x); ha[1] = f2b(fa.y); ha[2] = f2b(fa.z); ha[3] = f2b(fa.w);
      ha[4] = f2b(fb.x); ha[5] = f2b(fb.y); ha[6] = f2b(fb.z); ha[7] = f2b(fb.w);
    } else ha = p ? rA1 : rA0;
    *reinterpret_cast<u16x8*>(&As[buf][tid]) = ha;
    *reinterpret_cast<u16x8*>(&Bs[buf][tid]) = p ? rB1 : rB0;
  };

  f32x4 acc[4][2] = {};
  auto compute = [&](int buf) {
    bf16x8 af[4], bfv[2];
#pragma unroll
    for (int m = 0; m < 4; ++m) af[m] = As[buf][(wr * 4 + m) * 64 + lane];
#pragma unroll
    for (int n = 0; n < 2; ++n) bfv[n] = Bs[buf][(wc * 2 + n) * 64 + lane];
#pragma unroll
    for (int m = 0; m < 4; ++m)
#pragma unroll
      for (int n = 0; n < 2; ++n)
        acc[m][n] = __builtin_amdgcn_mfma_f32_16x16x32_bf16(af[m], bfv[n], acc[m][n], 0, 0, 0);
  };

  // prologue: loads for ks=0,1; stage ks=0 into buf0
  loadA(0, 0); loadB(0, 0);
  loadA(1, 1); loadB(1, 1);
  writeLDS(0, 0);
  // steady loop, 2 K-steps per trip (static reg-set indices)
  for (int ks0 = 0; ; ks0 += 2) {
    // --- sub-iter p=0: compute buf0 (data ks0); reg set0 free
    if (ks0 + 2 < NK) { loadA(ks0 + 2, 0); loadB(ks0 + 2, 0); }
    __syncthreads();
    compute(0);
    if (ks0 + 1 >= NK) break;
    writeLDS(1, 1);
    // --- sub-iter p=1: compute buf1 (data ks0+1); reg set1 free
    if (ks0 + 3 < NK) { loadA(ks0 + 3, 1); loadB(ks0 + 3, 1); }
    __syncthreads();
    compute(1);
    if (ks0 + 2 >= NK) break;
    writeLDS(0, 0);
  }

  // C/D layout: col = lane&15, row = (lane>>4)*4 + reg
  const int r4 = (lane >> 4) << 2;
  const int cc = lane & 15;
#pragma unroll
  for (int m = 0; m < 4; ++m)
#pragma unroll
    for (int n = 0; n < 2; ++n)
#pragma unroll
      for (int r = 0; r < 4; ++r) {
        int lr = wr * 64 + m * 16 + r4 + r;
        int lc = wc * 32 + n * 16 + cc;
        float vv = acc[m][n][r];
        if (MODE == M_QKV) {
          ((u16*)Cv)[(size_t)(row0 + lr) * QKV_LD + col0 + lc] = f2b(vv);
        } else if (MODE == M_OUT) {
          ((float*)Cv)[(size_t)(row0 + lr) * HH + col0 + lc] = vv;
        } else if (MODE == M_OUTER) {
          ((float*)Cv)[(size_t)t64 * (MM * MM) + (size_t)(row0 + lr) * MM + col0 + lc] = vv * scale;
        } else {  // M_RETR
          size_t rowg = (size_t)(2 * by + (lr >> 6)) * SS + (size_t)t64 * CHUNK + (lr & 63);
          ((u16*)Cv)[rowg * MM + col0 + lc] = f2b(vv);
        }
      }
}

// ---------------------------------------------------------------------------
// Fused l2norm + transpose: qkv cols [256,512)=k, [512,768)=v -> kT,vT
// [256][16384] bf16. Block = 64 rows; LDS transpose tile.
// ---------------------------------------------------------------------------
__global__ __launch_bounds__(256) void l2normT_kernel(const u16* __restrict__ qkv,
                                                      u16* __restrict__ kT,
                                                      u16* __restrict__ vT) {
  __shared__ u16 T[256][72];
  __shared__ float ps[64][4];
  __shared__ float inv[64];
  const int tid = threadIdx.x;
  const int q = tid >> 6, rl = tid & 63;
  const int row0 = blockIdx.x * 64;
#pragma unroll 1
  for (int seg = 0; seg < 2; ++seg) {
    u16* dstT = seg ? vT : kT;
    const int segbase = 256 + seg * 256;
    float ss = 0.f;
#pragma unroll
    for (int i = 0; i < 8; ++i) {
      u16x8 v = *reinterpret_cast<const u16x8*>(
          qkv + (size_t)(row0 + rl) * QKV_LD + segbase + q * 64 + i * 8);
#pragma unroll
      for (int e = 0; e < 8; ++e) {
        float f = b2f(v[e]);
        ss += f * f;
        T[q * 64 + i * 8 + e][rl] = v[e];
      }
    }
    ps[rl][q] = ss;
    __syncthreads();
    if (tid < 64) {
      float s = ps[tid][0] + ps[tid][1] + ps[tid][2] + ps[tid][3];
      inv[tid] = 1.0f / fmaxf(sqrtf(s), 1e-12f);
    }
    __syncthreads();
#pragma unroll
    for (int p = 0; p < 8; ++p) {
      int c = p * 32 + q * 8 + (rl >> 3);
      int r0 = (rl & 7) * 8;
      u16x8 val = *reinterpret_cast<const u16x8*>(&T[c][r0]);
      u16x8 o;
#pragma unroll
      for (int e = 0; e < 8; ++e) o[e] = f2b(b2f(val[e]) * inv[r0 + e]);
      *reinterpret_cast<u16x8*>(dstT + (size_t)c * ROWS + row0 + r0) = o;
    }
    __syncthreads();
  }
}

// ---------------------------------------------------------------------------
// Decay prefix over t: Mprev_b[t] = bf16(run); run = decay*run + outer[t].
// ---------------------------------------------------------------------------
__global__ __launch_bounds__(256) void prefix_kernel(const float* __restrict__ outer,
                                                     const float* __restrict__ M0,
                                                     u16* __restrict__ Mprev_b,
                                                     float decay_c) {
  int ij = blockIdx.x * 256 + threadIdx.x;
  float run = M0[ij];
  float pre[8];
#pragma unroll
  for (int d = 0; d < 8; ++d) pre[d] = outer[(size_t)d * (MM * MM) + ij];
#pragma unroll 1
  for (int tb = 0; tb < NCHUNK; tb += 8) {
#pragma unroll
    for (int d = 0; d < 8; ++d) {
      int tc = tb + d;
      float o = pre[d];
      if (tb + 8 < NCHUNK) pre[d] = outer[(size_t)(tc + 8) * (MM * MM) + ij];
      Mprev_b[(size_t)tc * (MM * MM) + ij] = f2b(run);
      run = decay_c * run + o;
    }
  }
}

// ---------------------------------------------------------------------------
extern "C" void kernel_launch(void* const* d_in, const int* in_sizes, int n_in,
                              void* d_out, int out_size, void* d_ws, size_t ws_size,
                              hipStream_t stream) {
  const float* x  = (const float*)d_in[0];
  const float* Wq = (const float*)d_in[1];
  const float* Wk = (const float*)d_in[2];
  const float* Wv = (const float*)d_in[3];
  const float* Wo = (const float*)d_in[4];
  const float* M0 = (const float*)d_in[5];
  float* out = (float*)d_out;

  char* ws = (char*)d_ws;
  u16*   qkv_b   = (u16*)(ws);               // 16384x768 bf16 (24M)
  u16*   kT      = (u16*)(ws + 25165824);    // 256x16384 bf16 (8M)
  u16*   vT      = (u16*)(ws + 33554432);    // 256x16384 bf16 (8M)
  float* outer   = (float*)(ws + 41943040);  // 64x256x256 fp32 (16M)
  u16*   Mprev_b = (u16*)(ws + 25165824);    // 8M, over dead kT (after OUTER)
  u16*   r_b     = (u16*)(ws + 33554432);    // 8M, over dead vT (after OUTER)
  u16*   Wqkv_b  = (u16*)(ws + 58720256);    // 768x1024 bf16 (1.5M)
  u16*   Wo_b    = (u16*)(ws + 60293120);    // 1024x256 bf16 (0.5M)

  const float scale   = 1.0f / (BB * CHUNK);
  const float decay_c = (float)pow(DECAY_F, (double)CHUNK);
  dim3 blk512(512), blk(256);

  // 1) weight casts (x is consumed fp32 directly by the QKV GEMM)
  cast_w_kernel<<<1024, blk, 0, stream>>>(Wq, Wk, Wv, Wo, Wqkv_b, Wo_b);
  // 2) fused cast + QKV projection: (16384x1024 f32)x(768x1024 bf16)^T -> qkv_b
  gemm_v2<M_QKV><<<dim3(QKV_LD / 128, ROWS / 128), blk512, 0, stream>>>(
      x, Wqkv_b, qkv_b, 0.f);
  // 3) l2norm k,v + transpose -> kT, vT
  l2normT_kernel<<<ROWS / 64, blk, 0, stream>>>(qkv_b, kT, vT);
  // 4) per-chunk outer products: outer[t] = scale * vT_t * kT_t^T
  gemm_v2<M_OUTER><<<dim3(2, 2, NCHUNK), blk512, 0, stream>>>(
      vT, kT, outer, scale);
  // 5) decay prefix scan -> Mprev_b (bf16)
  prefix_kernel<<<(MM * MM) / 256, blk, 0, stream>>>(outer, M0, Mprev_b, decay_c);
  // 6) retrieval: r = q @ Mprev_b[t]^T -> r_b (bf16)
  gemm_v2<M_RETR><<<dim3(2, 2, NCHUNK), blk512, 0, stream>>>(
      qkv_b, Mprev_b, r_b, 0.f);
  // 7) output projection: (16384x256)x(1024x256)^T -> fp32 out
  gemm_v2<M_OUT><<<dim3(HH / 128, ROWS / 128), blk512, 0, stream>>>(
      r_b, Wo_b, out, 0.f);
}

// Round 7
// 140.836 us; speedup vs baseline: 4.3535x; 1.0674x over previous
//
#include <hip/hip_runtime.h>
#include <math.h>

// Problem constants: B=4, S=4096, H=1024, M=256, chunk=64
#define BB 4
#define SS 4096
#define HH 1024
#define MM 256
#define CHUNK 64
#define NCHUNK 64
#define ROWS (BB*SS)          // 16384
#define QKV_LD 768
#define DECAY_F 0.99

typedef unsigned short u16;
typedef __attribute__((ext_vector_type(8))) short bf16x8;
typedef __attribute__((ext_vector_type(8))) unsigned short u16x8;
typedef __attribute__((ext_vector_type(4))) float f32x4;

__device__ inline u16 f2b(float f) {
  union { float f; unsigned u; } v; v.f = f;
  unsigned r = v.u + 0x7FFF + ((v.u >> 16) & 1);   // RNE
  return (u16)(r >> 16);
}
__device__ inline float b2f(u16 h) {
  union { unsigned u; float f; } v; v.u = ((unsigned)h) << 16; return v.f;
}

// async global->LDS, 16B per lane. LDS dest wave-uniform base; global src per-lane.
__device__ inline void gload16(const void* g, void* l) {
  __builtin_amdgcn_global_load_lds(
      (const __attribute__((address_space(1))) unsigned int*)g,
      (__attribute__((address_space(3))) unsigned int*)l, 16, 0, 0);
}

// ---------------------------------------------------------------------------
// fp32 -> bf16 cast of x
// ---------------------------------------------------------------------------
__global__ __launch_bounds__(256) void cast_x_kernel(const float* __restrict__ src,
                                                     u16* __restrict__ dst) {
  int i = blockIdx.x * 256 + threadIdx.x;
  float4 v = reinterpret_cast<const float4*>(src)[i];
  ushort4 o;
  o.x = f2b(v.x); o.y = f2b(v.y); o.z = f2b(v.z); o.w = f2b(v.w);
  reinterpret_cast<ushort4*>(dst)[i] = o;
}

// all 4 weight casts in one launch
__global__ __launch_bounds__(256) void cast_w_kernel(const float* __restrict__ Wq,
                                                     const float* __restrict__ Wk,
                                                     const float* __restrict__ Wv,
                                                     const float* __restrict__ Wo,
                                                     u16* __restrict__ Wqkv_b,
                                                     u16* __restrict__ Wo_b) {
  int b = blockIdx.x, which = b >> 8;
  int i = ((b & 255) << 8) + threadIdx.x;
  const float* src = which == 0 ? Wq : which == 1 ? Wk : which == 2 ? Wv : Wo;
  u16* dst = which < 3 ? Wqkv_b + which * (MM * HH) : Wo_b;
  float4 v = reinterpret_cast<const float4*>(src)[i];
  ushort4 o;
  o.x = f2b(v.x); o.y = f2b(v.y); o.z = f2b(v.z); o.w = f2b(v.w);
  reinterpret_cast<ushort4*>(dst)[i] = o;
}

// ---------------------------------------------------------------------------
// 256x256 8-phase MFMA GEMM (C = A * B^T), 512 thr = 8 waves (2M x 4N),
// wave tile 128x64, BK=64 (2 ksub of 32), fragment-major conflict-free LDS,
// gload_lds staging, counted vmcnt(2) once per K-tile, setprio MFMA clusters.
// Per K-tile: 4 phases x {ds_read subtile | 2 gload_lds (kt+1 -> dead dbuf)
//   -> barrier -> 16 MFMA (one quadrant x K=64) -> barrier}.
// ---------------------------------------------------------------------------
template<int OUT_BF16>
__global__ __launch_bounds__(512, 2) void gemm256(const u16* __restrict__ A,
                                                  const u16* __restrict__ B,
                                                  void* __restrict__ Cv,
                                                  int K, int lda, int ldb, int ldc) {
  // [dbuf][A=0/B=1][ksub][tile16][lane] : 2*2*2*16*64*16B = 128 KB
  __shared__ bf16x8 LD[2][2][2][16][64];
  const int tid = threadIdx.x, lane = tid & 63, wv = tid >> 6;
  const int wr = wv >> 2, wc = wv & 3;            // 2 x 4 wave grid

  // XCD-chunked bijective swizzle (nwg % 8 == 0 for both uses: 192, 256)
  const int gx = gridDim.x;
  const int nwg = gx * gridDim.y;
  const int lin = blockIdx.y * gx + blockIdx.x;
  const int chunk = nwg >> 3;
  const int orig = (lin & 7) * chunk + (lin >> 3);
  const int bx = orig % gx, by = orig / gx;
  const int row0 = by * 256, col0 = bx * 256;
  const int NT = K >> 6;

  const int fr = lane & 15;            // row within a 16-row tile
  const int kg = (lane >> 4) << 3;     // k-offset within a 32-wide ksub

  // stage one part (2 gload_lds): part 0: A tiles wv | 1: A wv+8 | 2: B wv | 3: B wv+8
  auto stage2 = [&](int kt, int db, int part) {
    const int ab = part >> 1;
    const int j = part & 1;
    const int tile = wv + (j << 3);            // wave-uniform
    const u16* base = ab ? B : A;
    const int ld = ab ? ldb : lda;
    const int rc0 = ab ? col0 : row0;
    const u16* g = base + (size_t)(rc0 + tile * 16 + fr) * ld + kt * 64 + kg;
    gload16(g,      &LD[db][ab][0][tile][0]);
    gload16(g + 32, &LD[db][ab][1][tile][0]);
  };

  bf16x8 aq[4][2], bq[4][2];
  auto readAquad = [&](int db, int h) {
#pragma unroll
    for (int i = 0; i < 4; ++i)
#pragma unroll
      for (int s = 0; s < 2; ++s)
        aq[i][s] = LD[db][0][s][wr * 8 + h * 4 + i][lane];
  };
  auto readB2 = [&](int db, int nh) {
#pragma unroll
    for (int j = 0; j < 2; ++j)
#pragma unroll
      for (int s = 0; s < 2; ++s)
        bq[nh * 2 + j][s] = LD[db][1][s][wc * 4 + nh * 2 + j][lane];
  };

  f32x4 acc[8][4] = {};
  auto cluster = [&](int h, int nh) {
#pragma unroll
    for (int i = 0; i < 4; ++i)
#pragma unroll
      for (int j = 0; j < 2; ++j)
#pragma unroll
        for (int s = 0; s < 2; ++s)
          acc[h * 4 + i][nh * 2 + j] = __builtin_amdgcn_mfma_f32_16x16x32_bf16(
              aq[i][s], bq[nh * 2 + j][s], acc[h * 4 + i][nh * 2 + j], 0, 0, 0);
  };

  // prologue: fully stage K-tile 0 into dbuf 0
  stage2(0, 0, 0); stage2(0, 0, 1); stage2(0, 0, 2); stage2(0, 0, 3);

  for (int kt = 0; kt < NT; ++kt) {
    const int db = kt & 1;
    const bool pf = (kt + 1 < NT);
    // ---- phase 0: quadrant (h=0, nh=0) ----
    if (pf) stage2(kt + 1, db ^ 1, 0);
    if (pf) asm volatile("s_waitcnt vmcnt(2)" ::: "memory");  // kt landed; 2 newest fly
    else    asm volatile("s_waitcnt vmcnt(0)" ::: "memory");
    __builtin_amdgcn_s_barrier();        // every wave's kt staging visible
    asm volatile("" ::: "memory");       // pin reads below the barrier
    readAquad(db, 0);
    readB2(db, 0);
    __builtin_amdgcn_s_setprio(1); cluster(0, 0); __builtin_amdgcn_s_setprio(0);
    __builtin_amdgcn_s_barrier();
    // ---- phase 1: quadrant (0,1) ----
    readB2(db, 1);
    if (pf) stage2(kt + 1, db ^ 1, 1);
    __builtin_amdgcn_s_barrier();
    __builtin_amdgcn_s_setprio(1); cluster(0, 1); __builtin_amdgcn_s_setprio(0);
    __builtin_amdgcn_s_barrier();
    // ---- phase 2: quadrant (1,0) ----
    readAquad(db, 1);
    if (pf) stage2(kt + 1, db ^ 1, 2);
    __builtin_amdgcn_s_barrier();
    __builtin_amdgcn_s_setprio(1); cluster(1, 0); __builtin_amdgcn_s_setprio(0);
    __builtin_amdgcn_s_barrier();
    // ---- phase 3: quadrant (1,1) ----
    if (pf) stage2(kt + 1, db ^ 1, 3);
    __builtin_amdgcn_s_barrier();
    __builtin_amdgcn_s_setprio(1); cluster(1, 1); __builtin_amdgcn_s_setprio(0);
    __builtin_amdgcn_s_barrier();
  }

  // C/D layout: col = lane&15, row = (lane>>4)*4 + reg
  const int r4 = (lane >> 4) << 2;
  const int cc = lane & 15;
#pragma unroll
  for (int mi = 0; mi < 8; ++mi)
#pragma unroll
    for (int nj = 0; nj < 4; ++nj)
#pragma unroll
      for (int r = 0; r < 4; ++r) {
        int lr = wr * 128 + mi * 16 + r4 + r;
        int lc = wc * 64 + nj * 16 + cc;
        float vv = acc[mi][nj][r];
        if (OUT_BF16) ((u16*)Cv)[(size_t)(row0 + lr) * ldc + col0 + lc] = f2b(vv);
        else          ((float*)Cv)[(size_t)(row0 + lr) * ldc + col0 + lc] = vv;
      }
}

// ---------------------------------------------------------------------------
// 128x128 MFMA GEMM (round-5 proven), depth-3 gload_lds pipeline, counted
// vmcnt. Used for the small batched modes only.
// ---------------------------------------------------------------------------
#define M_OUTER 2   // A=vT,B=kT (ld 16384), K=256 per chunk t, C=outer[t]*scale
#define M_RETR  3   // A=q (qkv ld 768, chunk rows), B=Mprev_b[t] bf16 (ld 256)

template<int MODE>
__global__ __launch_bounds__(256) void gemm128(const u16* __restrict__ A,
                                               const u16* __restrict__ Bg,
                                               void* __restrict__ Cv,
                                               int K, int lda, int ldb,
                                               float scale) {
  __shared__ bf16x8 As[3][512];
  __shared__ bf16x8 Bs[3][512];
  const int tid = threadIdx.x, lane = tid & 63, wv = tid >> 6;
  const int wr = wv >> 1, wc = wv & 1;
  const int t = blockIdx.z;
  const int bx = blockIdx.x, by = blockIdx.y;
  const int row0 = by * 128;
  const int col0 = bx * 128;
  const int NK = K >> 5;
  const u16* Bbase = (MODE == M_RETR) ? (Bg + (size_t)t * (MM * MM)) : Bg;

  auto stage = [&](int ks, int buf) {
    int koff;
    if (MODE == M_OUTER) koff = ((ks >> 1) << 12) + t * CHUNK + ((ks & 1) << 5);
    else                 koff = ks << 5;
#pragma unroll
    for (int j = 0; j < 2; ++j) {
      int m = j * 4 + wv;
      int rf = m * 16 + (lane & 15);
      size_t arow;
      if (MODE == M_RETR)
        arow = (size_t)(2 * by + (rf >> 6)) * SS + (size_t)t * CHUNK + (rf & 63);
      else
        arow = (size_t)(row0 + rf);
      const u16* ga = A + arow * (size_t)lda + koff + ((lane >> 4) << 3);
      gload16(ga, &As[buf][m * 64]);
      const u16* gb = Bbase + (size_t)(col0 + rf) * ldb + koff + ((lane >> 4) << 3);
      gload16(gb, &Bs[buf][m * 64]);
    }
  };

  f32x4 acc[4][4] = {};
  stage(0, 0);
  stage(1, 1);
  int rb = 0, sb = 2;
  for (int ks = 0; ks < NK; ++ks) {
    if (ks + 1 < NK) asm volatile("s_waitcnt vmcnt(4)" ::: "memory");
    else             asm volatile("s_waitcnt vmcnt(0)" ::: "memory");
    __builtin_amdgcn_s_barrier();
    asm volatile("" ::: "memory");
    if (ks + 2 < NK) stage(ks + 2, sb);
    bf16x8 af[4], bfr[4];
#pragma unroll
    for (int m = 0; m < 4; ++m) af[m] = As[rb][(wr * 4 + m) * 64 + lane];
#pragma unroll
    for (int n = 0; n < 4; ++n) bfr[n] = Bs[rb][(wc * 4 + n) * 64 + lane];
#pragma unroll
    for (int m = 0; m < 4; ++m)
#pragma unroll
      for (int n = 0; n < 4; ++n)
        acc[m][n] = __builtin_amdgcn_mfma_f32_16x16x32_bf16(af[m], bfr[n], acc[m][n], 0, 0, 0);
    rb = (rb == 2) ? 0 : rb + 1;
    sb = (sb == 2) ? 0 : sb + 1;
  }

  const int r4 = (lane >> 4) << 2;
  const int cc = lane & 15;
#pragma unroll
  for (int m = 0; m < 4; ++m)
#pragma unroll
    for (int n = 0; n < 4; ++n)
#pragma unroll
      for (int r = 0; r < 4; ++r) {
        int lr = wr * 64 + m * 16 + r4 + r;
        int lc = wc * 64 + n * 16 + cc;
        float vv = acc[m][n][r];
        if (MODE == M_OUTER) {
          ((float*)Cv)[(size_t)t * (MM * MM) + (size_t)(row0 + lr) * MM + col0 + lc] = vv * scale;
        } else {  // M_RETR
          size_t rowg = (size_t)(2 * by + (lr >> 6)) * SS + (size_t)t * CHUNK + (lr & 63);
          ((u16*)Cv)[rowg * MM + col0 + lc] = f2b(vv);
        }
      }
}

// ---------------------------------------------------------------------------
// Fused l2norm + transpose: qkv cols [256,512)=k, [512,768)=v -> kT,vT
// ---------------------------------------------------------------------------
__global__ __launch_bounds__(256) void l2normT_kernel(const u16* __restrict__ qkv,
                                                      u16* __restrict__ kT,
                                                      u16* __restrict__ vT) {
  __shared__ u16 T[256][72];
  __shared__ float ps[64][4];
  __shared__ float inv[64];
  const int tid = threadIdx.x;
  const int q = tid >> 6, rl = tid & 63;
  const int row0 = blockIdx.x * 64;
#pragma unroll 1
  for (int seg = 0; seg < 2; ++seg) {
    u16* dstT = seg ? vT : kT;
    const int segbase = 256 + seg * 256;
    float ss = 0.f;
#pragma unroll
    for (int i = 0; i < 8; ++i) {
      u16x8 v = *reinterpret_cast<const u16x8*>(
          qkv + (size_t)(row0 + rl) * QKV_LD + segbase + q * 64 + i * 8);
#pragma unroll
      for (int e = 0; e < 8; ++e) {
        float f = b2f(v[e]);
        ss += f * f;
        T[q * 64 + i * 8 + e][rl] = v[e];
      }
    }
    ps[rl][q] = ss;
    __syncthreads();
    if (tid < 64) {
      float s = ps[tid][0] + ps[tid][1] + ps[tid][2] + ps[tid][3];
      inv[tid] = 1.0f / fmaxf(sqrtf(s), 1e-12f);
    }
    __syncthreads();
#pragma unroll
    for (int p = 0; p < 8; ++p) {
      int c = p * 32 + q * 8 + (rl >> 3);
      int r0 = (rl & 7) * 8;
      u16x8 val = *reinterpret_cast<const u16x8*>(&T[c][r0]);
      u16x8 o;
#pragma unroll
      for (int e = 0; e < 8; ++e) o[e] = f2b(b2f(val[e]) * inv[r0 + e]);
      *reinterpret_cast<u16x8*>(dstT + (size_t)c * ROWS + row0 + r0) = o;
    }
    __syncthreads();
  }
}

// ---------------------------------------------------------------------------
// Decay prefix over t: Mprev_b[t] = bf16(run); run = decay*run + outer[t].
// ---------------------------------------------------------------------------
__global__ __launch_bounds__(256) void prefix_kernel(const float* __restrict__ outer,
                                                     const float* __restrict__ M0,
                                                     u16* __restrict__ Mprev_b,
                                                     float decay_c) {
  int ij = blockIdx.x * 256 + threadIdx.x;
  float run = M0[ij];
  float pre[8];
#pragma unroll
  for (int d = 0; d < 8; ++d) pre[d] = outer[(size_t)d * (MM * MM) + ij];
#pragma unroll 1
  for (int tb = 0; tb < NCHUNK; tb += 8) {
#pragma unroll
    for (int d = 0; d < 8; ++d) {
      int tc = tb + d;
      float o = pre[d];
      if (tb + 8 < NCHUNK) pre[d] = outer[(size_t)(tc + 8) * (MM * MM) + ij];
      Mprev_b[(size_t)tc * (MM * MM) + ij] = f2b(run);
      run = decay_c * run + o;
    }
  }
}

// ---------------------------------------------------------------------------
extern "C" void kernel_launch(void* const* d_in, const int* in_sizes, int n_in,
                              void* d_out, int out_size, void* d_ws, size_t ws_size,
                              hipStream_t stream) {
  const float* x  = (const float*)d_in[0];
  const float* Wq = (const float*)d_in[1];
  const float* Wk = (const float*)d_in[2];
  const float* Wv = (const float*)d_in[3];
  const float* Wo = (const float*)d_in[4];
  const float* M0 = (const float*)d_in[5];
  float* out = (float*)d_out;

  char* ws = (char*)d_ws;
  u16*   xb      = (u16*)(ws);               // 16384x1024 bf16 (32M)
  u16*   qkv_b   = (u16*)(ws + 33554432);    // 16384x768 bf16 (24M)
  u16*   Wqkv_b  = (u16*)(ws + 58720256);    // 768x1024 bf16 (1.5M)
  u16*   Wo_b    = (u16*)(ws + 60293120);    // 1024x256 bf16 (0.5M)
  u16*   kT      = (u16*)(ws);               // 8M, over dead xb
  u16*   vT      = (u16*)(ws + 8388608);     // 8M
  float* outer   = (float*)(ws + 16777216);  // 64x256x256 fp32 (16M)
  u16*   Mprev_b = (u16*)(ws);               // 8M, over dead kT
  u16*   r_b     = (u16*)(ws + 8388608);     // 8M, over dead vT

  const float scale   = 1.0f / (BB * CHUNK);
  const float decay_c = (float)pow(DECAY_F, (double)CHUNK);
  dim3 blk(256), blk512(512);

  // 1) casts
  cast_x_kernel<<<(ROWS * HH / 4) / 256, blk, 0, stream>>>(x, xb);
  cast_w_kernel<<<1024, blk, 0, stream>>>(Wq, Wk, Wv, Wo, Wqkv_b, Wo_b);
  // 2) fused QKV projection: (16384x1024)x(768x1024)^T -> qkv_b (8-phase 256^2)
  gemm256<1><<<dim3(QKV_LD / 256, ROWS / 256), blk512, 0, stream>>>(
      xb, Wqkv_b, qkv_b, HH, HH, HH, QKV_LD);
  // 3) l2norm k,v + transpose -> kT, vT
  l2normT_kernel<<<ROWS / 64, blk, 0, stream>>>(qkv_b, kT, vT);
  // 4) per-chunk outer products: outer[t] = scale * vT_t * kT_t^T
  gemm128<M_OUTER><<<dim3(2, 2, NCHUNK), blk, 0, stream>>>(
      vT, kT, outer, MM, ROWS, ROWS, scale);
  // 5) decay prefix scan -> Mprev_b (bf16)
  prefix_kernel<<<(MM * MM) / 256, blk, 0, stream>>>(outer, M0, Mprev_b, decay_c);
  // 6) retrieval: r = q @ Mprev_b[t]^T -> r_b (bf16)
  gemm128<M_RETR><<<dim3(2, 2, NCHUNK), blk, 0, stream>>>(
      qkv_b, Mprev_b, r_b, MM, QKV_LD, MM, 0.f);
  // 7) output projection: (16384x256)x(1024x256)^T -> fp32 out (8-phase 256^2)
  gemm256<0><<<dim3(HH / 256, ROWS / 256), blk512, 0, stream>>>(
      r_b, Wo_b, out, MM, MM, MM, HH);
}